// Round 20
// baseline (2644.042 us; speedup 1.0000x reference)
//
#include <hip/hip_runtime.h>
#include <hip/hip_bf16.h>
#include <math.h>

// EquiformerV2 block, fp32 activations. Round 26: node_sum edge loop gets T14
// async-STAGE prefetch — edge j+4's winv/oe are global_load'ed into REGISTERS
// before computing edge j, hiding ~600-900cy HBM latency under the 532-FMA
// rotation (was fully serialized: load -> compute -> load...). Same loads/order
// -> numerics identical. mlpf grid-concat 2x (r25: deg+rad0 blocks || rad1
// blocks, one dispatch), rad bf16, msg reads bf16 rad (r17), rmsnorms fused
// into producers (r22), msg+logits fused (r20), attn_gemm 19-tile MFMA (r14),
// FFN/energy split-bf16 MFMA (r9). E=40000, N=2000, NL=2.

#define NRBF 600
#define DIN 728
#define GPTS 288
#define CH 8

typedef __attribute__((ext_vector_type(8))) short bf16x8;
typedef __attribute__((ext_vector_type(4))) float f32x4;

__constant__ int d_mg[19] = {0,1,0,1,2,1,0,1,2,2,1,0,1,2,2,1,0,1,2};
__constant__ int d_loc[25] = {0,1,1,1,2,2,2,2,2,3,3,3,3,3,3,3,4,4,4,4,4,4,4,4,4};
__constant__ int d_mg0[5]={0,2,6,11,16};
__constant__ int d_mg1[8]={1,3,5,7,10,12,15,17};
__constant__ int d_mg2[6]={4,8,9,13,14,18};

__device__ inline float silu_f(float v){ return v/(1.0f+__expf(-v)); }
__device__ inline float bf2f(unsigned short u){ return __uint_as_float(((unsigned)u)<<16); }
__device__ inline unsigned short f2bf(float f){
  unsigned b=__float_as_uint(f);
  return (unsigned short)((b + 0x7FFF + ((b>>16)&1)) >> 16);
}

__device__ inline void atomicMaxF(float* addr, float val){
  int* ia=(int*)addr;
  int old=*ia;
  while (__int_as_float(old) < val){
    int assumed=old;
    old = atomicCAS(ia, assumed, __float_as_int(val));
    if (old == assumed) break;
  }
}

// ---------------- CSR build ----------------
__global__ __launch_bounds__(256) void zero_cnt_kernel(int* cnt, int N){
  int i = blockIdx.x*256+threadIdx.x;
  if (i<N) cnt[i]=0;
}
__global__ __launch_bounds__(256) void csr_count_kernel(const int* __restrict__ rcv, int* cnt, int E){
  int i = blockIdx.x*256+threadIdx.x;
  if (i<E) atomicAdd(&cnt[rcv[i]],1);
}
__global__ __launch_bounds__(256) void csr_scan_kernel(const int* __restrict__ cnt,
    int* rowptr, int* fill, int N){
  __shared__ int s_part[256];
  int tid=threadIdx.x;
  int chunk=(N+255)/256;
  int lvals[12];
  int base=tid*chunk;
  int lsum=0;
  for (int i=0;i<chunk && i<12;i++){
    int v=(base+i<N)?cnt[base+i]:0;
    lvals[i]=lsum; lsum+=v;
  }
  s_part[tid]=lsum;
  __syncthreads();
  if (tid==0){
    int run=0;
    for (int t=0;t<256;t++){ int v=s_part[t]; s_part[t]=run; run+=v; }
  }
  __syncthreads();
  int off=s_part[tid];
  for (int i=0;i<chunk && i<12;i++){
    if (base+i<N){ rowptr[base+i]=off+lvals[i]; fill[base+i]=off+lvals[i]; }
  }
  if (tid==255) rowptr[N]=off+lsum;
}
__global__ __launch_bounds__(256) void csr_fill_kernel(const int* __restrict__ rcv,
    int* fill, int* eix, int E){
  int i = blockIdx.x*256+threadIdx.x;
  if (i<E){ int p=atomicAdd(&fill[rcv[i]],1); eix[p]=i; }
}

// ---------------- fused so2W@valW -> bf16 wsvb, MFMA-B-fragment packed ----------------
__global__ __launch_bounds__(256) void wsvb_kernel(const float* __restrict__ so2W,
    const float* __restrict__ valW, unsigned short* __restrict__ wsvb){
  int i=blockIdx.x/3, g=blockIdx.x%3;
  const float* A = so2W + (size_t)i*24576 + g*8192;   // [128][64]
  const float* B = valW + (size_t)i*24576 + g*8192;   // [64][128]
  unsigned short* C = wsvb + (size_t)blockIdx.x*16384;
  __shared__ float sB[8192];
  for (int j=threadIdx.x;j<2048;j+=256) ((float4*)sB)[j]=((const float4*)B)[j];
  __syncthreads();
  for (int idx=threadIdx.x; idx<16384; idx+=256){
    int k=idx>>7, j=idx&127;
    float acc=0;
    #pragma unroll 4
    for (int o=0;o<64;o++) acc += A[k*64+o]*sB[o*128+j];
    int pos = ((k>>5)*8 + (j>>4))*512 + (((k>>3)&3)*16 + (j&15))*8 + (k&7);
    C[pos]=f2bf(acc);
  }
}

// ---------------- projW -> bf16 [6][128][64], MFMA-B-fragment packed ----------------
__global__ __launch_bounds__(256) void projb_kernel(const float* __restrict__ pW,
    unsigned short* __restrict__ projb){
  const float* src = pW + (size_t)blockIdx.x*8192;
  unsigned short* dst = projb + (size_t)blockIdx.x*8192;
  for (int idx=threadIdx.x; idx<8192; idx+=256){
    int k=idx>>6, j=idx&63;
    int pos = ((k>>5)*4 + (j>>4))*512 + (((k>>3)&3)*16 + (j&15))*8 + (k&7);
    dst[pos]=f2bf(src[idx]);
  }
}

// ---------------- generic B-fragment packer, hi/lo split, K zero-padded to 32 ----------------
__global__ __launch_bounds__(256) void packB2g_kernel(const float* __restrict__ src,
    unsigned short* __restrict__ dh, unsigned short* __restrict__ dl, int K, int Nn){
  int ktiles=(K+31)>>5;
  int nnt=Nn>>4;
  int tot=ktiles*nnt*512;
  for (int idx=blockIdx.x*256+threadIdx.x; idx<tot; idx+=gridDim.x*256){
    int f=idx>>9, r=idx&511, lane=r>>3, j=r&7;
    int kt=f/nnt, nt=f-kt*nnt;
    int k=kt*32+(lane>>4)*8+j, c=nt*16+(lane&15);
    float v=(k<K)? src[k*Nn+c] : 0.0f;
    unsigned short h=f2bf(v);
    dh[idx]=h;
    dl[idx]=f2bf(v-bf2f(h));
  }
}

// ---------------- tg [288][25] -> A-frags per 16-row tile (K=32 pad), hi/lo ----------------
__global__ __launch_bounds__(256) void pack_tg2_kernel(const float* __restrict__ tg,
    unsigned short* __restrict__ tgp){   // hi [0..9216) | lo [9216..18432)
  int tid=threadIdx.x;
  for (int idx=tid; idx<9216; idx+=256){
    int t=idx>>9, r=idx&511, lane=r>>3, j=r&7;
    int kl=(lane>>4)*8+j, row=t*16+(lane&15);
    float v=(kl<25)? tg[row*25+kl] : 0.0f;
    unsigned short h=f2bf(v);
    tgp[idx]=h;
    tgp[9216+idx]=f2bf(v-bf2f(h));
  }
}

// ---------------- fg [25][288] -> A-frags [t][mt] (M pad 32, K=16 valid of 32), hi/lo ----------------
__global__ __launch_bounds__(256) void pack_fg2_kernel(const float* __restrict__ fg,
    unsigned short* __restrict__ fgp){   // hi [0..18432) | lo [18432..36864)
  int tid=threadIdx.x;
  for (int idx=tid; idx<18432; idx+=256){
    int f=idx>>9, r=idx&511, lane=r>>3, j=r&7;
    int t=f>>1, mt=f&1;
    int row=mt*16+(lane&15), k=(lane>>4)*8+j;
    float v=(row<25 && k<16)? fg[row*288+t*16+k] : 0.0f;
    unsigned short h=f2bf(v);
    fgp[idx]=h;
    fgp[18432+idx]=f2bf(v-bf2f(h));
  }
}

// ---------------- fused MLP, 2x grid: blocks [0,nb0) deg+rad0, [nb0,2nb0) rad1-only ------
__global__ __launch_bounds__(256) void mlpf_kernel(const float* __restrict__ ev,
    const float* __restrict__ ese, const int* __restrict__ nsp,
    const unsigned short* __restrict__ dw1h, const unsigned short* __restrict__ dw1l,
    const float* __restrict__ db1,
    const unsigned short* __restrict__ dw2h, const unsigned short* __restrict__ dw2l,
    const float* __restrict__ db2,
    const unsigned short* __restrict__ r1h0, const unsigned short* __restrict__ r1l0,
    const float* __restrict__ rb10,
    const unsigned short* __restrict__ r2h0, const unsigned short* __restrict__ r2l0,
    const float* __restrict__ rb20,
    const unsigned short* __restrict__ r1h1, const unsigned short* __restrict__ r1l1,
    const float* __restrict__ rb11,
    const unsigned short* __restrict__ r2h1, const unsigned short* __restrict__ r2l1,
    const float* __restrict__ rb21,
    const int* __restrict__ snd, const int* __restrict__ rcv, const int* __restrict__ eix,
    unsigned short* __restrict__ degout,
    unsigned short* __restrict__ rad0out, unsigned short* __restrict__ rad1out,
    int nb0, int E){
  int tid=threadIdx.x, wv=tid>>6, lane=tid&63;
  int lanelo=lane&15, khi=lane>>4;
  int do_deg = (blockIdx.x < (unsigned)nb0) ? 1 : 0;
  int bb = do_deg ? blockIdx.x : (blockIdx.x - nb0);
  int p0=bb*16;
  const unsigned short* r1h = do_deg? r1h0 : r1h1;
  const unsigned short* r1l = do_deg? r1l0 : r1l1;
  const float* rb1 = do_deg? rb10 : rb11;
  const unsigned short* r2h = do_deg? r2h0 : r2h1;
  const unsigned short* r2l = do_deg? r2l0 : r2l1;
  const float* rb2 = do_deg? rb20 : rb21;
  unsigned short* radout = do_deg? rad0out : rad1out;
  __shared__ unsigned short s_eeh[4096], s_eel[4096];   // CH ktiles
  __shared__ unsigned short s_h1h[2048], s_h1l[2048];   // [16][128] swizzled
  __shared__ float s_d[16]; __shared__ int s_ss[16], s_rs[16], s_e[16];
  if (tid<16){
    int p=p0+tid;
    int e=(p<E)? eix[p] : -1;
    s_e[tid]=e;
    if (e>=0){
      float vx=ev[3*e], vy=ev[3*e+1], vz=ev[3*e+2];
      s_d[tid]=sqrtf(vx*vx+vy*vy+vz*vz+1e-12f);
      s_ss[tid]=nsp[snd[e]]; s_rs[tid]=nsp[rcv[e]];
    } else { s_d[tid]=0.0f; s_ss[tid]=0; s_rs[tid]=0; }
  }
  __syncthreads();
  const float step=5.0f/599.0f, inv_std=1.0f/(2.0f*step);
  int nta=wv*2, ntb=nta+1;
  f32x4 z4={0,0,0,0};
  f32x4 aD0=z4,aD1=z4,aR0=z4,aR1=z4;
  for (int c=0;c<23;c+=CH){
    int ncur=23-c; if (ncur>CH) ncur=CH;
    for (int idx=tid; idx<ncur*512; idx+=256){
      int f=idx>>9, r=idx&511, ln=r>>3, j=r&7;
      int k=(c+f)*32+((ln>>4)<<3)+j, row=ln&15;
      float v=0.0f;
      if (k<NRBF){ float t=(s_d[row]-k*step)*inv_std; v=__expf(-0.5f*t*t); }
      else if (k<NRBF+64) v=ese[s_ss[row]*128+(k-NRBF)];
      else if (k<DIN)     v=ese[s_rs[row]*128+64+(k-NRBF-64)];
      unsigned short h=f2bf(v);
      s_eeh[idx]=h; s_eel[idx]=f2bf(v-bf2f(h));
    }
    __syncthreads();
    for (int f=0; f<ncur; f++){
      int kt=c+f;
      bf16x8 Ah=*(const bf16x8*)(s_eeh + f*512 + lane*8);
      bf16x8 Al=*(const bf16x8*)(s_eel + f*512 + lane*8);
      size_t ba=(size_t)(kt*8+nta)*512+lane*8;
      {
        bf16x8 Bh=*(const bf16x8*)(r1h+ba), Bl=*(const bf16x8*)(r1l+ba);
        bf16x8 Bh2=*(const bf16x8*)(r1h+ba+512), Bl2=*(const bf16x8*)(r1l+ba+512);
        aR0=__builtin_amdgcn_mfma_f32_16x16x32_bf16(Ah,Bh,aR0,0,0,0);
        aR0=__builtin_amdgcn_mfma_f32_16x16x32_bf16(Al,Bh,aR0,0,0,0);
        aR0=__builtin_amdgcn_mfma_f32_16x16x32_bf16(Ah,Bl,aR0,0,0,0);
        aR1=__builtin_amdgcn_mfma_f32_16x16x32_bf16(Ah,Bh2,aR1,0,0,0);
        aR1=__builtin_amdgcn_mfma_f32_16x16x32_bf16(Al,Bh2,aR1,0,0,0);
        aR1=__builtin_amdgcn_mfma_f32_16x16x32_bf16(Ah,Bl2,aR1,0,0,0);
      }
      if (do_deg){
        bf16x8 Bh=*(const bf16x8*)(dw1h+ba), Bl=*(const bf16x8*)(dw1l+ba);
        bf16x8 Bh2=*(const bf16x8*)(dw1h+ba+512), Bl2=*(const bf16x8*)(dw1l+ba+512);
        aD0=__builtin_amdgcn_mfma_f32_16x16x32_bf16(Ah,Bh,aD0,0,0,0);
        aD0=__builtin_amdgcn_mfma_f32_16x16x32_bf16(Al,Bh,aD0,0,0,0);
        aD0=__builtin_amdgcn_mfma_f32_16x16x32_bf16(Ah,Bl,aD0,0,0,0);
        aD1=__builtin_amdgcn_mfma_f32_16x16x32_bf16(Ah,Bh2,aD1,0,0,0);
        aD1=__builtin_amdgcn_mfma_f32_16x16x32_bf16(Al,Bh2,aD1,0,0,0);
        aD1=__builtin_amdgcn_mfma_f32_16x16x32_bf16(Ah,Bl2,aD1,0,0,0);
      }
    }
    __syncthreads();
  }
  int nmlp = do_deg ? 2 : 1;
  #pragma unroll 1
  for (int it=0; it<nmlp; it++){
    int is_deg = (it==1);
    f32x4 a0 = is_deg ? aD0 : aR0;
    f32x4 a1 = is_deg ? aD1 : aR1;
    const float* b1 = is_deg ? db1 : rb1;
    #pragma unroll
    for (int q=0;q<4;q++){
      int row=khi*4+q;
      {
        int col=nta*16+lanelo;
        float v=silu_f(a0[q]+b1[col]);
        int pos=row*128 + (((col>>3)^(row&7))<<3) + (col&7);
        unsigned short h=f2bf(v);
        s_h1h[pos]=h; s_h1l[pos]=f2bf(v-bf2f(h));
      }
      {
        int col=ntb*16+lanelo;
        float v=silu_f(a1[q]+b1[col]);
        int pos=row*128 + (((col>>3)^(row&7))<<3) + (col&7);
        unsigned short h=f2bf(v);
        s_h1h[pos]=h; s_h1l[pos]=f2bf(v-bf2f(h));
      }
    }
    __syncthreads();
    bf16x8 Ahh[4],Ahl[4];
    #pragma unroll
    for (int kt=0;kt<4;kt++){
      int o=lanelo*128 + (((kt*4+khi)^(lanelo&7))<<3);
      Ahh[kt]=*(const bf16x8*)(s_h1h+o);
      Ahl[kt]=*(const bf16x8*)(s_h1l+o);
    }
    __syncthreads();
    if (is_deg){
      for (int nt=wv; nt<76; nt+=4){
        f32x4 acc=z4;
        #pragma unroll
        for (int kt=0;kt<4;kt++){
          size_t bo=(size_t)(kt*76+nt)*512+lane*8;
          bf16x8 Bh=*(const bf16x8*)(dw2h+bo), Bl=*(const bf16x8*)(dw2l+bo);
          acc=__builtin_amdgcn_mfma_f32_16x16x32_bf16(Ahh[kt],Bh,acc,0,0,0);
          acc=__builtin_amdgcn_mfma_f32_16x16x32_bf16(Ahl[kt],Bh,acc,0,0,0);
          acc=__builtin_amdgcn_mfma_f32_16x16x32_bf16(Ahh[kt],Bl,acc,0,0,0);
        }
        int col=nt*16+lanelo;
        float bb2=db2[col];
        #pragma unroll
        for (int q=0;q<4;q++){
          int p=p0+khi*4+q;
          if (p<E) degout[(size_t)p*1216+col]=f2bf(acc[q]+bb2);
        }
      }
    } else {
      for (int nt=wv; nt<24; nt+=4){
        f32x4 acc=z4;
        #pragma unroll
        for (int kt=0;kt<4;kt++){
          size_t bo=(size_t)(kt*24+nt)*512+lane*8;
          bf16x8 Bh=*(const bf16x8*)(r2h+bo), Bl=*(const bf16x8*)(r2l+bo);
          acc=__builtin_amdgcn_mfma_f32_16x16x32_bf16(Ahh[kt],Bh,acc,0,0,0);
          acc=__builtin_amdgcn_mfma_f32_16x16x32_bf16(Ahl[kt],Bh,acc,0,0,0);
          acc=__builtin_amdgcn_mfma_f32_16x16x32_bf16(Ahh[kt],Bl,acc,0,0,0);
        }
        int col=nt*16+lanelo;
        float bb2=rb2[col];
        #pragma unroll
        for (int q=0;q<4;q++){
          int e=s_e[khi*4+q];
          if (e>=0) radout[(size_t)e*384+col]=f2bf(acc[q]+bb2);
        }
      }
    }
  }
}

// ---------------- wave-per-edge node gather + register PREFETCH + FUSED rms-norm ----------
// mode 0: x += sum, oe strided (attn layout), xn = norm(x)*nw.
// mode 1: x = base + 0.05*sum, oe contiguous (deg layout), xn = norm(x)*nw.
// Edge j+4's winv/oe prefetched into regs before computing edge j (T14 overlap).
__global__ __launch_bounds__(256) void node_sum_kernel(const unsigned short* __restrict__ msgb,
    const float* __restrict__ winv, const int* __restrict__ rowptr, const int* __restrict__ eix,
    const int* __restrict__ nsp, const float* __restrict__ spe,
    const float* __restrict__ nw, float* __restrict__ x, float* __restrict__ xn,
    int mode, int N){
  int n=blockIdx.x, tid=threadIdx.x, wv=tid>>6, lane=tid&63;
  __shared__ float s_winv[4][480];
  __shared__ unsigned short s_oe[4][1216];
  __shared__ float4 s_red[4][400];
  __shared__ float4 s_ms4[16];
  int row0=rowptr[n];
  int cnt=rowptr[n+1]-row0;
  float4 acc[7];
  #pragma unroll
  for (int t=0;t<7;t++) acc[t]=make_float4(0,0,0,0);
  float wpre[8];
  int4 opre[3];
  int j=wv;
  if (j<cnt){
    int p=row0+j;
    int e=eix[p];
    #pragma unroll
    for (int t=0;t<8;t++){ int k=lane+t*64; wpre[t]=(k<475)? winv[(size_t)e*475+k] : 0.0f; }
    if (mode==1){
      #pragma unroll
      for (int t=0;t<3;t++){
        int k=lane+t*64;
        opre[t]=(k<152)? *(const int4*)(msgb+(size_t)p*1216+(size_t)k*8) : make_int4(0,0,0,0);
      }
    } else {
      #pragma unroll
      for (int t=0;t<3;t++){
        int k=lane+t*64;
        if (k<152){ int m=k>>3, jj=k&7; opre[t]=*(const int4*)(msgb+(size_t)p*2432+m*128+jj*8); }
        else opre[t]=make_int4(0,0,0,0);
      }
    }
  }
  for (; j<cnt; j+=4){
    // WAR guard: previous compute's LDS reads must retire before overwriting slices
    asm volatile("s_waitcnt lgkmcnt(0)" ::: "memory");
    #pragma unroll
    for (int t=0;t<8;t++){ int k=lane+t*64; if (k<475) s_winv[wv][k]=wpre[t]; }
    #pragma unroll
    for (int t=0;t<3;t++){ int k=lane+t*64; if (k<152) ((int4*)s_oe[wv])[k]=opre[t]; }
    // issue prefetch for edge j+4 NOW — overlaps with compute below
    int jn=j+4;
    if (jn<cnt){
      int p=row0+jn;
      int e=eix[p];
      #pragma unroll
      for (int t=0;t<8;t++){ int k=lane+t*64; wpre[t]=(k<475)? winv[(size_t)e*475+k] : 0.0f; }
      if (mode==1){
        #pragma unroll
        for (int t=0;t<3;t++){
          int k=lane+t*64;
          opre[t]=(k<152)? *(const int4*)(msgb+(size_t)p*1216+(size_t)k*8) : make_int4(0,0,0,0);
        }
      } else {
        #pragma unroll
        for (int t=0;t<3;t++){
          int k=lane+t*64;
          if (k<152){ int m=k>>3, jj=k&7; opre[t]=*(const int4*)(msgb+(size_t)p*2432+m*128+jj*8); }
          else opre[t]=make_int4(0,0,0,0);
        }
      }
    }
    asm volatile("s_waitcnt lgkmcnt(0)" ::: "memory");
    const unsigned* o2=(const unsigned*)s_oe[wv];
    #pragma unroll
    for (int t=0;t<7;t++){
      int sI=lane+t*64;
      if (sI<400){
        int l=sI>>4, c4=sI&15;
        const float* wr=s_winv[wv]+l*19;
        float4 a=acc[t];
        #pragma unroll
        for (int m=0;m<19;m++){
          float w=wr[m];
          unsigned ua=o2[m*32+c4*2], ub=o2[m*32+c4*2+1];
          a.x+=w*bf2f((unsigned short)(ua&0xffffu));
          a.y+=w*bf2f((unsigned short)(ua>>16));
          a.z+=w*bf2f((unsigned short)(ub&0xffffu));
          a.w+=w*bf2f((unsigned short)(ub>>16));
        }
        acc[t]=a;
      }
    }
  }
  asm volatile("s_waitcnt lgkmcnt(0)" ::: "memory");
  #pragma unroll
  for (int t=0;t<7;t++){
    int sI=lane+t*64;
    if (sI<400) s_red[wv][sI]=acc[t];
  }
  __syncthreads();
  float4* xp=(float4*)(x+(size_t)n*1600);
  int j0=tid, j1=tid+256;
  bool h1=(j1<400);
  float4 v0, v1=make_float4(0,0,0,0);
  if (mode==0){
    {
      float4 a=s_red[0][j0], b=s_red[1][j0], c=s_red[2][j0], d=s_red[3][j0];
      float4 cur=xp[j0];
      cur.x+=a.x+b.x+c.x+d.x;
      cur.y+=a.y+b.y+c.y+d.y;
      cur.z+=a.z+b.z+c.z+d.z;
      cur.w+=a.w+b.w+c.w+d.w;
      v0=cur; xp[j0]=cur;
    }
    if (h1){
      float4 a=s_red[0][j1], b=s_red[1][j1], c=s_red[2][j1], d=s_red[3][j1];
      float4 cur=xp[j1];
      cur.x+=a.x+b.x+c.x+d.x;
      cur.y+=a.y+b.y+c.y+d.y;
      cur.z+=a.z+b.z+c.z+d.z;
      cur.w+=a.w+b.w+c.w+d.w;
      v1=cur; xp[j1]=cur;
    }
  } else {
    int sp=nsp[n];
    const float4* sp4=(const float4*)(spe+(size_t)sp*64);
    {
      int l=j0>>4, c4=j0&15;
      float4 a=s_red[0][j0], b=s_red[1][j0], c=s_red[2][j0], d=s_red[3][j0];
      float4 base=(l==0)? sp4[c4] : make_float4(0,0,0,0);
      float4 o;
      o.x=base.x+0.05f*(a.x+b.x+c.x+d.x);
      o.y=base.y+0.05f*(a.y+b.y+c.y+d.y);
      o.z=base.z+0.05f*(a.z+b.z+c.z+d.z);
      o.w=base.w+0.05f*(a.w+b.w+c.w+d.w);
      v0=o; xp[j0]=o;
    }
    if (h1){
      float4 a=s_red[0][j1], b=s_red[1][j1], c=s_red[2][j1], d=s_red[3][j1];
      float4 o;
      o.x=0.05f*(a.x+b.x+c.x+d.x);
      o.y=0.05f*(a.y+b.y+c.y+d.y);
      o.z=0.05f*(a.z+b.z+c.z+d.z);
      o.w=0.05f*(a.w+b.w+c.w+d.w);
      v1=o; xp[j1]=o;
    }
  }
  __syncthreads();   // all s_red reads done -> safe to alias as partial buffer
  float4* s_p4=(float4*)s_red;
  float4 a4;
  a4.x=v0.x*v0.x; a4.y=v0.y*v0.y; a4.z=v0.z*v0.z; a4.w=v0.w*v0.w;
  if (h1){ a4.x+=v1.x*v1.x; a4.y+=v1.y*v1.y; a4.z+=v1.z*v1.z; a4.w+=v1.w*v1.w; }
  s_p4[tid]=a4;
  __syncthreads();
  if (tid<16){
    float4 s=make_float4(0,0,0,0);
    #pragma unroll
    for (int k=0;k<16;k++){
      float4 p=s_p4[tid+16*k];
      s.x+=p.x; s.y+=p.y; s.z+=p.z; s.w+=p.w;
    }
    float4 m;
    m.x=rsqrtf(s.x*(1.0f/25.0f)+1e-6f);
    m.y=rsqrtf(s.y*(1.0f/25.0f)+1e-6f);
    m.z=rsqrtf(s.z*(1.0f/25.0f)+1e-6f);
    m.w=rsqrtf(s.w*(1.0f/25.0f)+1e-6f);
    s_ms4[tid]=m;
  }
  __syncthreads();
  float4* xnp=(float4*)(xn+(size_t)n*1600);
  {
    int l=j0>>4, g=j0&15;
    float4 m=s_ms4[g];
    const float* wr=nw + d_loc[l]*64 + g*4;
    float4 o;
    o.x=v0.x*m.x*wr[0]; o.y=v0.y*m.y*wr[1]; o.z=v0.z*m.z*wr[2]; o.w=v0.w*m.w*wr[3];
    xnp[j0]=o;
  }
  if (h1){
    int l=j1>>4, g=j1&15;
    float4 m=s_ms4[g];
    const float* wr=nw + d_loc[l]*64 + g*4;
    float4 o;
    o.x=v1.x*m.x*wr[0]; o.y=v1.y*m.y*wr[1]; o.z=v1.z*m.z*wr[2]; o.w=v1.w*m.w*wr[3];
    xnp[j1]=o;
  }
}

__global__ __launch_bounds__(256) void init_mxden_kernel(float* mx, float* den, int N){
  int idx = blockIdx.x*256+threadIdx.x;
  if (idx < N*8){ mx[idx]=-3.0e38f; den[idx]=0.0f; }
}

__global__ __launch_bounds__(256) void den_kernel(const float* __restrict__ logits,
    const float* __restrict__ mx, const int* __restrict__ rcv,
    float* __restrict__ den, int E){
  int idx = blockIdx.x*256+threadIdx.x;
  if (idx >= E*8) return;
  int e = idx>>3, hd = idx&7, r = rcv[e];
  atomicAdd(&den[r*8+hd], __expf(logits[idx]-mx[r*8+hd]));
}

// ---------------- pass 2a: msg + fused alpha-logits, wave-per-edge (4 edges/block) -----------
// rad read as bf16.
__global__ __launch_bounds__(256) void msg_kernel(const float* __restrict__ xn,
    const float* __restrict__ wig, const unsigned short* __restrict__ radb,
    const float* __restrict__ so2W, const float* __restrict__ alphaW, const float* __restrict__ alphaV,
    const int* __restrict__ snd, const int* __restrict__ rcv, const int* __restrict__ eix,
    unsigned short* __restrict__ msgb, float* __restrict__ logits, float* __restrict__ mx, int E){
  __shared__ float s_wig[1900];   // 4 waves x 475
  __shared__ float s_m0[4][128];
  __shared__ float s_sh0[4][64];
  int tid=threadIdx.x, wv=tid>>6, lane=tid&63;
  int p=blockIdx.x*4+wv;
  bool act=(p<E);
  int pc=act? p : (E-1);
  int e=eix[pc];
  int node=(lane<32)? snd[e] : rcv[e];
  int c2=(lane&31)*2;
  int col0=c2+((lane>>5)<<6);   // global col, even
  const float* xb=xn+(size_t)node*1600+c2;
  float ca[25], cb[25];
  #pragma unroll
  for (int l=0;l<25;l++){
    float2 v=*(const float2*)(xb+l*64);
    ca[l]=v.x; cb[l]=v.y;
  }
  float* swig=s_wig+wv*475;
  for (int j=lane;j<475;j+=64) swig[j]=wig[(size_t)e*475+j];
  float ra0,ra1,rb0,rb1,rc0,rc1;
  {
    const unsigned short* rb_=radb+(size_t)e*384;
    unsigned u0=*(const unsigned*)(rb_+col0);
    unsigned u1=*(const unsigned*)(rb_+128+col0);
    unsigned u2=*(const unsigned*)(rb_+256+col0);
    ra0=bf2f((unsigned short)(u0&0xffffu)); ra1=bf2f((unsigned short)(u0>>16));
    rb0=bf2f((unsigned short)(u1&0xffffu)); rb1=bf2f((unsigned short)(u1>>16));
    rc0=bf2f((unsigned short)(u2&0xffffu)); rc1=bf2f((unsigned short)(u2>>16));
  }
  __syncthreads();
  unsigned short* dst=msgb+(size_t)pc*2432+col0;
  constexpr int mgc[19]={0,1,0,1,2,1,0,1,2,2,1,0,1,2,2,1,0,1,2};
  float m0a=0.0f, m0b=0.0f;
  if (act){
    #pragma unroll
    for (int m=0;m<19;m++){
      float a0=0.0f,a1=0.0f;
      const float* wr=swig+m*25;
      #pragma unroll
      for (int l=0;l<25;l++){ float w=wr[l]; a0+=w*ca[l]; a1+=w*cb[l]; }
      float r0,r1;
      if (mgc[m]==0){ r0=ra0; r1=ra1; }
      else if (mgc[m]==1){ r0=rb0; r1=rb1; }
      else { r0=rc0; r1=rc1; }
      a0*=r0; a1*=r1;
      if (m==0){ m0a=a0; m0b=a1; }
      unsigned packv=((unsigned)f2bf(a1)<<16)|(unsigned)f2bf(a0);
      *(unsigned*)(dst+m*128)=packv;
    }
  }
  // ---- fused alpha-logits chain (wave-local; inactive waves compute garbage, writes guarded)
  s_m0[wv][col0]=m0a; s_m0[wv][col0+1]=m0b;
  asm volatile("s_waitcnt lgkmcnt(0)" ::: "memory");
  {
    const float* m0p=s_m0[wv];
    float accs=0.0f;
    #pragma unroll 8
    for (int k=0;k<128;k++) accs += m0p[k]*so2W[k*64+lane];
    s_sh0[wv][lane]=silu_f(accs);
  }
  asm volatile("s_waitcnt lgkmcnt(0)" ::: "memory");
  {
    const float* sh=s_sh0[wv];
    int j0=lane*4;
    float4 av=*(const float4*)(alphaV+j0);
    float4 aacc={0,0,0,0};
    #pragma unroll 8
    for (int o=0;o<64;o++){
      float s=sh[o];
      float4 w=*(const float4*)(alphaW+o*256+j0);
      aacc.x+=s*w.x; aacc.y+=s*w.y; aacc.z+=s*w.z; aacc.w+=s*w.w;
    }
    float part = silu_f(aacc.x)*av.x + silu_f(aacc.y)*av.y
               + silu_f(aacc.z)*av.z + silu_f(aacc.w)*av.w;
    part += __shfl_xor(part,1);
    part += __shfl_xor(part,2);
    part += __shfl_xor(part,4);
    if (act && (lane&7)==0){
      int h=lane>>3;
      int r=rcv[e];
      logits[(size_t)e*8+h]=part;
      atomicMaxF(&mx[r*8+h], part);
    }
  }
}

// ---------------- pass 2b: 16-edge MFMA GEMM: vv = msg@wsv (*attn), oe = vv@proj ----------------
__global__ __launch_bounds__(256) void attn_gemm_kernel(unsigned short* __restrict__ msgb,
    const unsigned short* __restrict__ wsvp, const unsigned short* __restrict__ projp,
    const float* __restrict__ logits, const float* __restrict__ mx, const float* __restrict__ den,
    const int* __restrict__ eix, const int* __restrict__ rcv, int E){
  int tid=threadIdx.x, wv=tid>>6, lane=tid&63;
  int lanelo=lane&15, khi=lane>>4;
  int p0=blockIdx.x*16;
  __shared__ unsigned short s_vv[2176];   // [16][136]
  __shared__ float s_attn[16][8];
  __shared__ short s_r2e[304], s_r2m[304];
  for (int j=tid;j<304;j+=256){
    int e,m;
    if (j<80){ e=j/5; m=d_mg0[j%5]; }
    else if (j<208){ int q=j-80; e=q>>3; m=d_mg1[q&7]; }
    else { int q=j-208; e=q/6; m=d_mg2[q%6]; }
    s_r2e[j]=(short)e; s_r2m[j]=(short)m;
  }
  if (tid<128){
    int i=tid>>3, h=tid&7, p=p0+i;
    float a=0.0f;
    if (p<E){
      int e=eix[p]; int r=rcv[e];
      a=__expf(logits[(size_t)e*8+h]-mx[r*8+h])/(den[r*8+h]+1e-12f);
    }
    s_attn[i][h]=a;
  }
  __syncthreads();
  const int4* wp4=(const int4*)wsvp;
  const int4* pp4=(const int4*)projp;
  for (int t=0;t<19;t++){
    int g=(t<5)?0:((t<13)?1:2);
    int R=t*16+lanelo;
    int ei=s_r2e[R], mi=s_r2m[R];
    int pp=p0+ei;
    size_t abase=((size_t)((pp<E)?pp:0))*2432 + (size_t)mi*128;
    bf16x8 A[4];
    #pragma unroll
    for (int kt=0;kt<4;kt++)
      A[kt]=*(const bf16x8*)(msgb + abase + kt*32 + khi*8);
    #pragma unroll
    for (int h2=0;h2<2;h2++){
      int nt=wv*2+h2;
      f32x4 acc={0,0,0,0};
      #pragma unroll
      for (int kt=0;kt<4;kt++){
        int4 tt=wp4[g*2048+(kt*8+nt)*64+lane];
        acc=__builtin_amdgcn_mfma_f32_16x16x32_bf16(A[kt],*(bf16x8*)&tt,acc,0,0,0);
      }
      int col=nt*16+lanelo;
      #pragma unroll
      for (int q=0;q<4;q++){
        int r16=khi*4+q;
        int ei2=s_r2e[t*16+r16];
        s_vv[r16*136+col]=f2bf(acc[q]*s_attn[ei2][nt]);
      }
    }
    __syncthreads();
    {
      bf16x8 A2[4];
      #pragma unroll
      for (int kt=0;kt<4;kt++)
        A2[kt]=*(const bf16x8*)(s_vv + lanelo*136 + kt*32 + khi*8);
      f32x4 acc={0,0,0,0};
      #pragma unroll
      for (int kt=0;kt<4;kt++){
        int4 tt=pp4[g*1024+(kt*4+wv)*64+lane];
        acc=__builtin_amdgcn_mfma_f32_16x16x32_bf16(A2[kt],*(bf16x8*)&tt,acc,0,0,0);
      }
      int col=wv*16+lanelo;
      #pragma unroll
      for (int q=0;q<4;q++){
        int R2=t*16+khi*4+q;
        int pi=p0+s_r2e[R2];
        if (pi<E) msgb[(size_t)pi*2432 + (size_t)s_r2m[R2]*128 + col]=f2bf(acc[q]);
      }
    }
    __syncthreads();
  }
}

// ---------------- S2 grid FFN via split-bf16 MFMA + FUSED next-layer rms-norm -------------
__global__ __launch_bounds__(256) void grid_ffn_mfma_kernel(const float* __restrict__ xnin,
    const unsigned short* __restrict__ tgp, const unsigned short* __restrict__ fgp,
    const unsigned short* __restrict__ w1p, const unsigned short* __restrict__ w2p,
    const float* __restrict__ b1, const float* __restrict__ nw,
    float* __restrict__ x, float* __restrict__ xnout, int N){
  int n=blockIdx.x, tid=threadIdx.x, wv=tid>>6, lane=tid&63;
  int lanelo=lane&15, khi=lane>>4;
  __shared__ __align__(16) char s_mem[74240];
  unsigned short* s_w1=(unsigned short*)s_mem;             // hi 8192 | lo 8192 shorts (32KB)
  unsigned short* s_xn=(unsigned short*)(s_mem+32768);     // hi 2048 | lo 2048 shorts (8KB)
  float* s_b1=(float*)(s_mem+40960);                       // 128 f
  unsigned short* scr=(unsigned short*)(s_mem+41472)+(size_t)wv*4096;  // 8KB/wave
  for (int j=tid;j<2048;j+=256) ((int4*)s_w1)[j]=((const int4*)w1p)[j];
  if (tid<128) s_b1[tid]=b1[tid];
  { int4 z={0,0,0,0}; for (int j=tid;j<512;j+=256) ((int4*)s_xn)[j]=z; }
  __syncthreads();
  {
    const float* xr=xnin+(size_t)n*1600;
    for (int j=tid;j<1600;j+=256){
      int k=j>>6, c=j&63;
      float v=xr[j];
      unsigned short h=f2bf(v);
      s_xn[c*32+k]=h;
      s_xn[2048+c*32+k]=f2bf(v-bf2f(h));
    }
  }
  __syncthreads();
  bf16x8 XBh[4],XBl[4];
  #pragma unroll
  for (int ct=0;ct<4;ct++){
    int o=(ct*16+lanelo)*32 + khi*8;
    XBh[ct]=*(const bf16x8*)(s_xn+o);
    XBl[ct]=*(const bf16x8*)(s_xn+2048+o);
  }
  f32x4 oacc[2][4];
  #pragma unroll
  for (int mt=0;mt<2;mt++)
    #pragma unroll
    for (int nt=0;nt<4;nt++){ f32x4 z={0,0,0,0}; oacc[mt][nt]=z; }
  for (int t=wv;t<18;t+=4){
    bf16x8 Atgh=*(const bf16x8*)(tgp + t*512 + lane*8);
    bf16x8 Atgl=*(const bf16x8*)(tgp + 9216 + t*512 + lane*8);
    #pragma unroll
    for (int ct=0;ct<4;ct++){
      f32x4 g={0,0,0,0};
      g=__builtin_amdgcn_mfma_f32_16x16x32_bf16(Atgh,XBh[ct],g,0,0,0);
      g=__builtin_amdgcn_mfma_f32_16x16x32_bf16(Atgl,XBh[ct],g,0,0,0);
      g=__builtin_amdgcn_mfma_f32_16x16x32_bf16(Atgh,XBl[ct],g,0,0,0);
      #pragma unroll
      for (int q=0;q<4;q++){
        int row=khi*4+q, col=ct*16+lanelo;
        int pos=row*64 + (((col>>3)^(row&7))<<3) + (col&7);
        float v=g[q]; unsigned short h=f2bf(v);
        scr[pos]=h; scr[1024+pos]=f2bf(v-bf2f(h));
      }
    }
    bf16x8 Agh[2],Agl[2];
    #pragma unroll
    for (int kt=0;kt<2;kt++){
      int o=lanelo*64 + (((kt*4+khi)^(lanelo&7))<<3);
      Agh[kt]=*(const bf16x8*)(scr+o);
      Agl[kt]=*(const bf16x8*)(scr+1024+o);
    }
    #pragma unroll
    for (int nt=0;nt<8;nt++){
      f32x4 h={0,0,0,0};
      #pragma unroll
      for (int kt=0;kt<2;kt++){
        bf16x8 Bh=*(const bf16x8*)(s_w1 + (kt*8+nt)*512 + lane*8);
        bf16x8 Bl=*(const bf16x8*)(s_w1 + 8192 + (kt*8+nt)*512 + lane*8);
        h=__builtin_amdgcn_mfma_f32_16x16x32_bf16(Agh[kt],Bh,h,0,0,0);
        h=__builtin_amdgcn_mfma_f32_16x16x32_bf16(Agl[kt],Bh,h,0,0,0);
        h=__builtin_amdgcn_mfma_f32_16x16x32_bf16(Agh[kt],Bl,h,0,0,0);
      }
      #pragma unroll
      for (int q=0;q<4;q++){
        int row=khi*4+q, col=nt*16+lanelo;
        float v=silu_f(h[q]+s_b1[col]);
        int pos=row*128 + (((col>>3)^(row&7))<<3) + (col&7);
        unsigned short hh=f2bf(v);
        scr[pos]=hh; scr[2048+pos]=f2bf(v-bf2f(hh));
      }
    }
    bf16x8 Ahh[4],Ahl[4];
    #pragma unroll
    for (int kt=0;kt<4;kt++){
      int o=lanelo*128 + (((kt*4+khi)^(lanelo&7))<<3);
      Ahh[kt]=*(const bf16x8*)(scr+o);
      Ahl[kt]=*(const bf16x8*)(scr+2048+o);
    }
    #pragma unroll
    for (int nt=0;nt<4;nt++){
      f32x4 o4={0,0,0,0};
      #pragma unroll
      for (int kt=0;kt<4;kt++){
        bf16x8 Bh=*(const bf16x8*)(w2p + (kt*4+nt)*512 + lane*8);
        bf16x8 Bl=*(const bf16x8*)(w2p + 8192 + (kt*4+nt)*512 + lane*8);
        o4=__builtin_amdgcn_mfma_f32_16x16x32_bf16(Ahh[kt],Bh,o4,0,0,0);
        o4=__builtin_amdgcn_mfma_f32_16x16x32_bf16(Ahl[kt],Bh,o4,0,0,0);
        o4=__builtin_amdgcn_mfma_f32_16x16x32_bf16(Ahh[kt],Bl,o4,0,0,0);
      }
      #pragma unroll
      for (int q=0;q<4;q++){
        int ch=nt*16+lanelo, rowk=khi*4+q;
        int pos=ch*32 + (((rowk>>3)^(ch&3))<<3) + (rowk&7);
        float v=o4[q]; unsigned short hh=f2bf(v);
        scr[pos]=hh; scr[2048+pos]=f2bf(v-bf2f(hh));
      }
    }
    bf16x8 Boh[4],Bol[4];
    #pragma unroll
    for (int nt=0;nt<4;nt++){
      int ch=nt*16+lanelo;
      int o=ch*32 + ((khi^(ch&3))<<3);
      Boh[nt]=*(const bf16x8*)(scr+o);
      Bol[nt]=*(const bf16x8*)(scr+2048+o);
    }
    #pragma unroll
    for (int mt=0;mt<2;mt++){
      bf16x8 Afh=*(const bf16x8*)(fgp + (t*2+mt)*512 + lane*8);
      bf16x8 Afl=*(const bf16x8*)(fgp + 18432 + (t*2+mt)*512 + lane*8);
      #pragma unroll
      for (int nt=0;nt<4;nt++){
        oacc[mt][nt]=__builtin_amdgcn_mfma_f32_16x16x32_bf16(Afh,Boh[nt],oacc[mt][nt],0,0,0);
        oacc[mt][nt]=__builtin_amdgcn_mfma_f32_16x16x32_bf16(Afl,Boh[nt],oacc[mt][nt],0,0,0);
        oacc[mt][nt]=__builtin_amdgcn_mfma_f32_16x16x32_bf16(Afh,Bol[nt],oacc[mt][nt],0,0,0);
      }
    }
  }
  __syncthreads();
  float* pout=(float*)s_mem;   // alias W1 region: 4 waves x [32][64] fp32 (32KB)
  #pragma unroll
  for (int mt=0;mt<2;mt++)
    #pragma unroll
    for (int nt=0;nt<4;nt++)
      #pragma unroll
      for (int q=0;q<4;q++){
        int row=mt*16+khi*4+q, col=nt*16+lanelo;
        pout[wv*2048 + row*64 + col]=oacc[mt][nt][q];
      }
  __syncthreads();
  const size_t nb=(size_t)n*1600;
  float accn=0.0f;
  for (int j=tid;j<1600;j+=256){
    float v = x[nb+j] + pout[j]+pout[2048+j]+pout[4096+j]+pout[6144+j];
    x[nb+j]=v;
    accn += v*v;
  }
  __syncthreads();   // pout reads done -> safe to alias
  float* s_part=(float*)s_mem;
  float* s_msv=((float*)s_mem)+256;
  s_part[tid]=accn;
  __syncthreads();
  if (tid<64){
    float m=(s_part[tid]+s_part[tid+64]+s_part[tid+128]+s_part[tid+192])*(1.0f/25.0f);
    s_msv[tid]=rsqrtf(m+1e-6f);
  }
  __syncthreads();
  for (int j=tid;j<1600;j+=256){
    int l=j>>6, c=j&63;
    xnout[nb+j]=x[nb+j]*s_msv[c]*nw[d_loc[l]*64+c];
  }
}

// ---------------- final energy head via split-bf16 MFMA ----------------
__global__ __launch_bounds__(256) void energy_mfma_kernel(const float* __restrict__ xn,
    const unsigned short* __restrict__ tgp, const float* __restrict__ fg,
    const unsigned short* __restrict__ enw1p, const float* __restrict__ b1,
    const float* __restrict__ w2, const float* __restrict__ b2,
    float* __restrict__ out, int N){
  int n=blockIdx.x, tid=threadIdx.x, wv=tid>>6, lane=tid&63;
  int lanelo=lane&15, khi=lane>>4;
  __shared__ __align__(16) char s_mem[59584];
  unsigned short* s_w1=(unsigned short*)s_mem;             // hi 8192 | lo 8192 shorts
  unsigned short* s_xn=(unsigned short*)(s_mem+32768);     // hi 2048 | lo 2048
  float* s_b1=(float*)(s_mem+40960);
  float* s_w2=(float*)(s_mem+41472);
  float* s_fg0=(float*)(s_mem+41984);                      // 288 f
  float* s_red=(float*)(s_mem+43136);
  unsigned short* scr=(unsigned short*)(s_mem+43200)+(size_t)wv*2048;  // 4KB/wave (g hi|lo)
  for (int j=tid;j<2048;j+=256) ((int4*)s_w1)[j]=((const int4*)enw1p)[j];
  if (tid<128){ s_b1[tid]=b1[tid]; s_w2[tid]=w2[tid]; }
  for (int j=tid;j<288;j+=256) s_fg0[j]=fg[j];
  { int4 z={0,0,0,0}; for (int j=tid;j<512;j+=256) ((int4*)s_xn)[j]=z; }
  __syncthreads();
  {
    const float* xr=xn+(size_t)n*1600;
    for (int j=tid;j<1600;j+=256){
      int k=j>>6, c=j&63;
      float v=xr[j];
      unsigned short h=f2bf(v);
      s_xn[c*32+k]=h;
      s_xn[2048+c*32+k]=f2bf(v-bf2f(h));
    }
  }
  __syncthreads();
  bf16x8 XBh[4],XBl[4];
  #pragma unroll
  for (int ct=0;ct<4;ct++){
    int o=(ct*16+lanelo)*32 + khi*8;
    XBh[ct]=*(const bf16x8*)(s_xn+o);
    XBl[ct]=*(const bf16x8*)(s_xn+2048+o);
  }
  float b2v=b2[0];
  float e=0.0f;
  for (int t=wv;t<18;t+=4){
    bf16x8 Atgh=*(const bf16x8*)(tgp + t*512 + lane*8);
    bf16x8 Atgl=*(const bf16x8*)(tgp + 9216 + t*512 + lane*8);
    #pragma unroll
    for (int ct=0;ct<4;ct++){
      f32x4 g={0,0,0,0};
      g=__builtin_amdgcn_mfma_f32_16x16x32_bf16(Atgh,XBh[ct],g,0,0,0);
      g=__builtin_amdgcn_mfma_f32_16x16x32_bf16(Atgl,XBh[ct],g,0,0,0);
      g=__builtin_amdgcn_mfma_f32_16x16x32_bf16(Atgh,XBl[ct],g,0,0,0);
      #pragma unroll
      for (int q=0;q<4;q++){
        int row=khi*4+q, col=ct*16+lanelo;
        int pos=row*64 + (((col>>3)^(row&7))<<3) + (col&7);
        float v=g[q]; unsigned short h=f2bf(v);
        scr[pos]=h; scr[1024+pos]=f2bf(v-bf2f(h));
      }
    }
    bf16x8 Agh[2],Agl[2];
    #pragma unroll
    for (int kt=0;kt<2;kt++){
      int o=lanelo*64 + (((kt*4+khi)^(lanelo&7))<<3);
      Agh[kt]=*(const bf16x8*)(scr+o);
      Agl[kt]=*(const bf16x8*)(scr+1024+o);
    }
    #pragma unroll
    for (int nt=0;nt<8;nt++){
      f32x4 h={0,0,0,0};
      #pragma unroll
      for (int kt=0;kt<2;kt++){
        bf16x8 Bh=*(const bf16x8*)(s_w1 + (kt*8+nt)*512 + lane*8);
        bf16x8 Bl=*(const bf16x8*)(s_w1 + 8192 + (kt*8+nt)*512 + lane*8);
        h=__builtin_amdgcn_mfma_f32_16x16x32_bf16(Agh[kt],Bh,h,0,0,0);
        h=__builtin_amdgcn_mfma_f32_16x16x32_bf16(Agl[kt],Bh,h,0,0,0);
        h=__builtin_amdgcn_mfma_f32_16x16x32_bf16(Agh[kt],Bl,h,0,0,0);
      }
      #pragma unroll
      for (int q=0;q<4;q++){
        int row=khi*4+q, col=nt*16+lanelo;
        float v=silu_f(h[q]+s_b1[col]);
        e += v*s_w2[col]*s_fg0[t*16+row];
      }
    }
    if (lanelo==0){
      #pragma unroll
      for (int q=0;q<4;q++) e += s_fg0[t*16+khi*4+q]*b2v;
    }
  }
  #pragma unroll
  for (int d=1;d<64;d<<=1) e += __shfl_xor(e,d);
  if (lane==0) s_red[wv]=e;
  __syncthreads();
  if (tid==0) out[n]=(s_red[0]+s_red[1]+s_red[2]+s_red[3])*(1.0f/2000.0f);
}

extern "C" void kernel_launch(void* const* d_in, const int* in_sizes, int n_in,
                              void* d_out, int out_size, void* d_ws, size_t ws_size,
                              hipStream_t stream){
  (void)n_in; (void)out_size; (void)ws_size;
  const float* ev   = (const float*)d_in[0];
  const float* wig  = (const float*)d_in[1];
  const float* winv = (const float*)d_in[2];
  const float* spe  = (const float*)d_in[3];
  const float* ese  = (const float*)d_in[4];
  const float* degW1= (const float*)d_in[5];
  const float* degb1= (const float*)d_in[6];
  const float* degW2= (const float*)d_in[7];
  const float* degb2= (const float*)d_in[8];
  const float* n1w  = (const float*)d_in[9];
  const float* radW1= (const float*)d_in[10];
  const float* radb1= (const float*)d_in[11];
  const float* radW2= (const float*)d_in[12];
  const float* radb2= (const float*)d_in[13];
  const float* so2W = (const float*)d_in[14];
  const float* aW   = (const float*)d_in[15];
  const float* aV   = (const float*)d_in[16];
  const float* vW   = (const float*)d_in[17];
  const float* pW   = (const float*)d_in[18];
  const float* n2w  = (const float*)d_in[19];
  const float* fW1  = (const float*)d_in[20];
  const float* fb1  = (const float*)d_in[21];
  const float* fW2  = (const float*)d_in[22];
  const float* tg   = (const float*)d_in[23];
  const float* fg   = (const float*)d_in[24];
  const float* fnw  = (const float*)d_in[25];
  const float* enW1 = (const float*)d_in[26];
  const float* enb1 = (const float*)d_in[27];
  const float* enW2 = (const float*)d_in[28];
  const float* enb2 = (const float*)d_in[29];
  const int* nsp = (const int*)d_in[30];
  const int* snd = (const int*)d_in[31];
  const int* rcv = (const int*)d_in[32];
  int N = in_sizes[30];
  int E = in_sizes[31];
  float* out = (float*)d_out;

  float* ws = (float*)d_ws;
  size_t off = 0;
  unsigned short* rad0b = (unsigned short*)(ws + off); off += (size_t)E*192;  // E*384 bf16
  unsigned short* rad1b = (unsigned short*)(ws + off); off += (size_t)E*192;  // E*384 bf16
  float* logits = ws + off; off += (size_t)E*8;
  float* mx     = ws + off; off += (size_t)N*8;
  float* den    = ws + off; off += (size_t)N*8;
  float* x      = ws + off; off += (size_t)N*1600;
  float* xn     = ws + off; off += (size_t)N*1600;
  unsigned short* wsvb  = (unsigned short*)(ws + off); off += (size_t)6*16384/2;
  unsigned short* projb = (unsigned short*)(ws + off); off += (size_t)6*8192/2;
  int* cnt      = (int*)(ws + off); off += (size_t)N;
  int* rowptr   = (int*)(ws + off); off += (size_t)(N+1);
  int* fill     = (int*)(ws + off); off += (size_t)N;
  int* eixbuf   = (int*)(ws + off); off += (size_t)E;
  off = (off + 3) & ~((size_t)3);                       // 16B-align
  unsigned short* msgb  = (unsigned short*)(ws + off); off += (size_t)E*1216;  // [E][19][128] bf16
  unsigned short* tgp   = (unsigned short*)(ws + off); off += 9216;    // hi+lo 18432 shorts
  unsigned short* fgp   = (unsigned short*)(ws + off); off += 18432;   // hi+lo 36864 shorts
  unsigned short* wwp   = (unsigned short*)(ws + off); off += 32768;   // 2 layers x (w1 hi/lo + w2 hi/lo)
  unsigned short* enw1p = (unsigned short*)(ws + off); off += 8192;    // hi+lo 16384 shorts
  unsigned short* degw1p = (unsigned short*)(ws + off); off += 94208;   // 23*8*512 *2
  unsigned short* degw2p = (unsigned short*)(ws + off); off += 155648;  // 4*76*512 *2
  unsigned short* radw1p = (unsigned short*)(ws + off); off += 94208*2; // per layer
  unsigned short* radw2p = (unsigned short*)(ws + off); off += 49152*2; // per layer

  // CSR by receiver + packed weights
  zero_cnt_kernel<<<(N+255)/256, 256, 0, stream>>>(cnt, N);
  csr_count_kernel<<<(E+255)/256, 256, 0, stream>>>(rcv, cnt, E);
  csr_scan_kernel<<<1, 256, 0, stream>>>(cnt, rowptr, fill, N);
  csr_fill_kernel<<<(E+255)/256, 256, 0, stream>>>(rcv, fill, eixbuf, E);
  wsvb_kernel<<<6, 256, 0, stream>>>(so2W, vW, wsvb);
  projb_kernel<<<6, 256, 0, stream>>>(pW, projb);
  pack_tg2_kernel<<<1, 256, 0, stream>>>(tg, tgp);
  pack_fg2_kernel<<<1, 256, 0, stream>>>(fg, fgp);
  for (int i=0;i<2;i++){
    unsigned short* wl = wwp + (size_t)i*32768;
    packB2g_kernel<<<8, 256, 0, stream>>>(fW1 + (size_t)i*8192, wl, wl+8192, 64, 128);
    packB2g_kernel<<<8, 256, 0, stream>>>(fW2 + (size_t)i*8192, wl+16384, wl+24576, 128, 64);
  }
  packB2g_kernel<<<8, 256, 0, stream>>>(enW1, enw1p, enw1p+8192, 64, 128);
  packB2g_kernel<<<32, 256, 0, stream>>>(degW1, degw1p, degw1p+94208, DIN, 128);
  packB2g_kernel<<<32, 256, 0, stream>>>(degW2, degw2p, degw2p+155648, 128, 1216);
  for (int i=0;i<2;i++){
    unsigned short* r1 = radw1p + (size_t)i*188416;
    unsigned short* r2 = radw2p + (size_t)i*98304;
    packB2g_kernel<<<32, 256, 0, stream>>>(radW1 + (size_t)i*DIN*128, r1, r1+94208, DIN, 128);
    packB2g_kernel<<<16, 256, 0, stream>>>(radW2 + (size_t)i*128*384, r2, r2+49152, 128, 384);
  }

  // ONE mlpf dispatch, 2x grid: deg+rad0 blocks + rad1-only blocks run concurrently
  int nb0 = (E+15)/16;
  mlpf_kernel<<<2*nb0, 256, 0, stream>>>(ev, ese, nsp,
      degw1p, degw1p+94208, degb1, degw2p, degw2p+155648, degb2,
      radw1p, radw1p+94208, radb1,
      radw2p, radw2p+49152, radb2,
      radw1p+188416, radw1p+188416+94208, radb1+128,
      radw2p+98304, radw2p+98304+49152, radb2+384,
      snd, rcv, eixbuf, msgb, rad0b, rad1b, nb0, E);
  node_sum_kernel<<<N, 256, 0, stream>>>(msgb, winv, rowptr, eixbuf, nsp, spe,
                                         n1w, x, xn, 1, N);

  for (int i=0;i<2;i++){
    init_mxden_kernel<<<(N*8+255)/256, 256, 0, stream>>>(mx, den, N);
    const unsigned short* radp = (i==0)? rad0b : rad1b;
    msg_kernel<<<(E+3)/4, 256, 0, stream>>>(xn, wig, radp,
                                            so2W + (size_t)i*24576,
                                            aW + (size_t)i*64*256, aV + (size_t)i*256,
                                            snd, rcv, eixbuf, msgb, logits, mx, E);
    den_kernel<<<(E*8+255)/256, 256, 0, stream>>>(logits, mx, rcv, den, E);
    attn_gemm_kernel<<<(E+15)/16, 256, 0, stream>>>(msgb,
                                                    wsvb + (size_t)i*3*16384, projb + (size_t)i*3*8192,
                                                    logits, mx, den, eixbuf, rcv, E);
    node_sum_kernel<<<N, 256, 0, stream>>>(msgb, winv, rowptr, eixbuf, nsp, spe,
                                           n2w + (size_t)i*320, x, xn, 0, N);
    const float* nxt = (i==0) ? (n1w + 320) : fnw;
    grid_ffn_mfma_kernel<<<N, 256, 0, stream>>>(xn, tgp, fgp,
                                                wwp + (size_t)i*32768, wwp + (size_t)i*32768 + 16384,
                                                fb1 + (size_t)i*128, nxt, x, xn, N);
  }
  energy_mfma_kernel<<<N, 256, 0, stream>>>(xn, tgp, fg, enw1p, enb1, enW2, enb2, out, N);
}

// Round 21
// 2515.593 us; speedup vs baseline: 1.0511x; 1.0511x over previous
//
#include <hip/hip_runtime.h>
#include <hip/hip_bf16.h>
#include <math.h>

// EquiformerV2 block, fp32 activations. Round 27: launch-overhead reduction via
// grid-concat (the r25-proven lever): 15 preamble pack launches -> ONE
// pack_all_kernel (block-range routed); init_mxden fused into node_sum's start
// (block n inits its own mx/den octet). Numerics identical. node_sum keeps r26
// prefetch (neutral). mlpf grid-concat 2x (r25), rad bf16 + msg reads bf16
// (r17), rmsnorms fused into producers (r22), msg+logits fused (r20),
// attn_gemm 19-tile MFMA (r14), FFN/energy split-bf16 MFMA (r9).
// E=40000, N=2000, NL=2.

#define NRBF 600
#define DIN 728
#define GPTS 288
#define CH 8

typedef __attribute__((ext_vector_type(8))) short bf16x8;
typedef __attribute__((ext_vector_type(4))) float f32x4;

__constant__ int d_mg[19] = {0,1,0,1,2,1,0,1,2,2,1,0,1,2,2,1,0,1,2};
__constant__ int d_loc[25] = {0,1,1,1,2,2,2,2,2,3,3,3,3,3,3,3,4,4,4,4,4,4,4,4,4};
__constant__ int d_mg0[5]={0,2,6,11,16};
__constant__ int d_mg1[8]={1,3,5,7,10,12,15,17};
__constant__ int d_mg2[6]={4,8,9,13,14,18};

__device__ inline float silu_f(float v){ return v/(1.0f+__expf(-v)); }
__device__ inline float bf2f(unsigned short u){ return __uint_as_float(((unsigned)u)<<16); }
__device__ inline unsigned short f2bf(float f){
  unsigned b=__float_as_uint(f);
  return (unsigned short)((b + 0x7FFF + ((b>>16)&1)) >> 16);
}

__device__ inline void atomicMaxF(float* addr, float val){
  int* ia=(int*)addr;
  int old=*ia;
  while (__int_as_float(old) < val){
    int assumed=old;
    old = atomicCAS(ia, assumed, __float_as_int(val));
    if (old == assumed) break;
  }
}

// ---------------- CSR build ----------------
__global__ __launch_bounds__(256) void zero_cnt_kernel(int* cnt, int N){
  int i = blockIdx.x*256+threadIdx.x;
  if (i<N) cnt[i]=0;
}
__global__ __launch_bounds__(256) void csr_count_kernel(const int* __restrict__ rcv, int* cnt, int E){
  int i = blockIdx.x*256+threadIdx.x;
  if (i<E) atomicAdd(&cnt[rcv[i]],1);
}
__global__ __launch_bounds__(256) void csr_scan_kernel(const int* __restrict__ cnt,
    int* rowptr, int* fill, int N){
  __shared__ int s_part[256];
  int tid=threadIdx.x;
  int chunk=(N+255)/256;
  int lvals[12];
  int base=tid*chunk;
  int lsum=0;
  for (int i=0;i<chunk && i<12;i++){
    int v=(base+i<N)?cnt[base+i]:0;
    lvals[i]=lsum; lsum+=v;
  }
  s_part[tid]=lsum;
  __syncthreads();
  if (tid==0){
    int run=0;
    for (int t=0;t<256;t++){ int v=s_part[t]; s_part[t]=run; run+=v; }
  }
  __syncthreads();
  int off=s_part[tid];
  for (int i=0;i<chunk && i<12;i++){
    if (base+i<N){ rowptr[base+i]=off+lvals[i]; fill[base+i]=off+lvals[i]; }
  }
  if (tid==255) rowptr[N]=off+lsum;
}
__global__ __launch_bounds__(256) void csr_fill_kernel(const int* __restrict__ rcv,
    int* fill, int* eix, int E){
  int i = blockIdx.x*256+threadIdx.x;
  if (i<E){ int p=atomicAdd(&fill[rcv[i]],1); eix[p]=i; }
}

// ---------------- packB2g as device fn (hi/lo split, K zero-padded to 32) ----------------
__device__ inline void packB2g_dev(const float* __restrict__ src,
    unsigned short* __restrict__ dh, unsigned short* __restrict__ dl,
    int K, int Nn, int b, int b0, int nb){
  int ktiles=(K+31)>>5;
  int nnt=Nn>>4;
  int tot=ktiles*nnt*512;
  for (int idx=(b-b0)*256+threadIdx.x; idx<tot; idx+=nb*256){
    int f=idx>>9, r=idx&511, lane=r>>3, j=r&7;
    int kt=f/nnt, nt=f-kt*nnt;
    int k=kt*32+(lane>>4)*8+j, c=nt*16+(lane&15);
    float v=(k<K)? src[k*Nn+c] : 0.0f;
    unsigned short h=f2bf(v);
    dh[idx]=h;
    dl[idx]=f2bf(v-bf2f(h));
  }
}

// ---------------- ONE preamble pack dispatch, block-range routed (210 blocks) -------------
// [0,6) wsvb | [6,12) projb | 12 tg | 13 fg | [14,210) packB2g jobs.
__global__ __launch_bounds__(256) void pack_all_kernel(
    const float* __restrict__ so2W, const float* __restrict__ valW, unsigned short* __restrict__ wsvb,
    const float* __restrict__ pW, unsigned short* __restrict__ projb,
    const float* __restrict__ tg, unsigned short* __restrict__ tgp,
    const float* __restrict__ fg, unsigned short* __restrict__ fgp,
    const float* __restrict__ fW1, const float* __restrict__ fW2, unsigned short* __restrict__ wwp,
    const float* __restrict__ enW1, unsigned short* __restrict__ enw1p,
    const float* __restrict__ degW1, unsigned short* __restrict__ degw1p,
    const float* __restrict__ degW2, unsigned short* __restrict__ degw2p,
    const float* __restrict__ radW1, unsigned short* __restrict__ radw1p,
    const float* __restrict__ radW2, unsigned short* __restrict__ radw2p){
  __shared__ float sB[8192];
  int b=blockIdx.x, tid=threadIdx.x;
  if (b<6){
    int i=b/3, g=b%3;
    const float* A = so2W + (size_t)i*24576 + g*8192;   // [128][64]
    const float* B = valW + (size_t)i*24576 + g*8192;   // [64][128]
    unsigned short* C = wsvb + (size_t)b*16384;
    for (int j=tid;j<2048;j+=256) ((float4*)sB)[j]=((const float4*)B)[j];
    __syncthreads();
    for (int idx=tid; idx<16384; idx+=256){
      int k=idx>>7, j=idx&127;
      float acc=0;
      #pragma unroll 4
      for (int o=0;o<64;o++) acc += A[k*64+o]*sB[o*128+j];
      int pos = ((k>>5)*8 + (j>>4))*512 + (((k>>3)&3)*16 + (j&15))*8 + (k&7);
      C[pos]=f2bf(acc);
    }
  } else if (b<12){
    int bb=b-6;
    const float* src = pW + (size_t)bb*8192;
    unsigned short* dst = projb + (size_t)bb*8192;
    for (int idx=tid; idx<8192; idx+=256){
      int k=idx>>6, j=idx&63;
      int pos = ((k>>5)*4 + (j>>4))*512 + (((k>>3)&3)*16 + (j&15))*8 + (k&7);
      dst[pos]=f2bf(src[idx]);
    }
  } else if (b==12){
    for (int idx=tid; idx<9216; idx+=256){
      int t=idx>>9, r=idx&511, lane=r>>3, j=r&7;
      int kl=(lane>>4)*8+j, row=t*16+(lane&15);
      float v=(kl<25)? tg[row*25+kl] : 0.0f;
      unsigned short h=f2bf(v);
      tgp[idx]=h;
      tgp[9216+idx]=f2bf(v-bf2f(h));
    }
  } else if (b==13){
    for (int idx=tid; idx<18432; idx+=256){
      int f=idx>>9, r=idx&511, lane=r>>3, j=r&7;
      int t=f>>1, mt=f&1;
      int row=mt*16+(lane&15), k=(lane>>4)*8+j;
      float v=(row<25 && k<16)? fg[row*288+t*16+k] : 0.0f;
      unsigned short h=f2bf(v);
      fgp[idx]=h;
      fgp[18432+idx]=f2bf(v-bf2f(h));
    }
  } else if (b<18){        // fW1 layer 0
    unsigned short* wl = wwp;
    packB2g_dev(fW1, wl, wl+8192, 64, 128, b, 14, 4);
  } else if (b<22){        // fW2 layer 0
    unsigned short* wl = wwp;
    packB2g_dev(fW2, wl+16384, wl+24576, 128, 64, b, 18, 4);
  } else if (b<26){        // fW1 layer 1
    unsigned short* wl = wwp + 32768;
    packB2g_dev(fW1+8192, wl, wl+8192, 64, 128, b, 22, 4);
  } else if (b<30){        // fW2 layer 1
    unsigned short* wl = wwp + 32768;
    packB2g_dev(fW2+8192, wl+16384, wl+24576, 128, 64, b, 26, 4);
  } else if (b<34){        // enW1
    packB2g_dev(enW1, enw1p, enw1p+8192, 64, 128, b, 30, 4);
  } else if (b<66){        // degW1
    packB2g_dev(degW1, degw1p, degw1p+94208, DIN, 128, b, 34, 32);
  } else if (b<114){       // degW2
    packB2g_dev(degW2, degw2p, degw2p+155648, 128, 1216, b, 66, 48);
  } else if (b<146){       // radW1 layer 0
    packB2g_dev(radW1, radw1p, radw1p+94208, DIN, 128, b, 114, 32);
  } else if (b<162){       // radW2 layer 0
    packB2g_dev(radW2, radw2p, radw2p+49152, 128, 384, b, 146, 16);
  } else if (b<194){       // radW1 layer 1
    unsigned short* r1 = radw1p + 188416;
    packB2g_dev(radW1+(size_t)DIN*128, r1, r1+94208, DIN, 128, b, 162, 32);
  } else {                 // radW2 layer 1 [194,210)
    unsigned short* r2 = radw2p + 98304;
    packB2g_dev(radW2+(size_t)128*384, r2, r2+49152, 128, 384, b, 194, 16);
  }
}

// ---------------- fused MLP, 2x grid: blocks [0,nb0) deg+rad0, [nb0,2nb0) rad1-only ------
__global__ __launch_bounds__(256) void mlpf_kernel(const float* __restrict__ ev,
    const float* __restrict__ ese, const int* __restrict__ nsp,
    const unsigned short* __restrict__ dw1h, const unsigned short* __restrict__ dw1l,
    const float* __restrict__ db1,
    const unsigned short* __restrict__ dw2h, const unsigned short* __restrict__ dw2l,
    const float* __restrict__ db2,
    const unsigned short* __restrict__ r1h0, const unsigned short* __restrict__ r1l0,
    const float* __restrict__ rb10,
    const unsigned short* __restrict__ r2h0, const unsigned short* __restrict__ r2l0,
    const float* __restrict__ rb20,
    const unsigned short* __restrict__ r1h1, const unsigned short* __restrict__ r1l1,
    const float* __restrict__ rb11,
    const unsigned short* __restrict__ r2h1, const unsigned short* __restrict__ r2l1,
    const float* __restrict__ rb21,
    const int* __restrict__ snd, const int* __restrict__ rcv, const int* __restrict__ eix,
    unsigned short* __restrict__ degout,
    unsigned short* __restrict__ rad0out, unsigned short* __restrict__ rad1out,
    int nb0, int E){
  int tid=threadIdx.x, wv=tid>>6, lane=tid&63;
  int lanelo=lane&15, khi=lane>>4;
  int do_deg = (blockIdx.x < (unsigned)nb0) ? 1 : 0;
  int bb = do_deg ? blockIdx.x : (blockIdx.x - nb0);
  int p0=bb*16;
  const unsigned short* r1h = do_deg? r1h0 : r1h1;
  const unsigned short* r1l = do_deg? r1l0 : r1l1;
  const float* rb1 = do_deg? rb10 : rb11;
  const unsigned short* r2h = do_deg? r2h0 : r2h1;
  const unsigned short* r2l = do_deg? r2l0 : r2l1;
  const float* rb2 = do_deg? rb20 : rb21;
  unsigned short* radout = do_deg? rad0out : rad1out;
  __shared__ unsigned short s_eeh[4096], s_eel[4096];   // CH ktiles
  __shared__ unsigned short s_h1h[2048], s_h1l[2048];   // [16][128] swizzled
  __shared__ float s_d[16]; __shared__ int s_ss[16], s_rs[16], s_e[16];
  if (tid<16){
    int p=p0+tid;
    int e=(p<E)? eix[p] : -1;
    s_e[tid]=e;
    if (e>=0){
      float vx=ev[3*e], vy=ev[3*e+1], vz=ev[3*e+2];
      s_d[tid]=sqrtf(vx*vx+vy*vy+vz*vz+1e-12f);
      s_ss[tid]=nsp[snd[e]]; s_rs[tid]=nsp[rcv[e]];
    } else { s_d[tid]=0.0f; s_ss[tid]=0; s_rs[tid]=0; }
  }
  __syncthreads();
  const float step=5.0f/599.0f, inv_std=1.0f/(2.0f*step);
  int nta=wv*2, ntb=nta+1;
  f32x4 z4={0,0,0,0};
  f32x4 aD0=z4,aD1=z4,aR0=z4,aR1=z4;
  for (int c=0;c<23;c+=CH){
    int ncur=23-c; if (ncur>CH) ncur=CH;
    for (int idx=tid; idx<ncur*512; idx+=256){
      int f=idx>>9, r=idx&511, ln=r>>3, j=r&7;
      int k=(c+f)*32+((ln>>4)<<3)+j, row=ln&15;
      float v=0.0f;
      if (k<NRBF){ float t=(s_d[row]-k*step)*inv_std; v=__expf(-0.5f*t*t); }
      else if (k<NRBF+64) v=ese[s_ss[row]*128+(k-NRBF)];
      else if (k<DIN)     v=ese[s_rs[row]*128+64+(k-NRBF-64)];
      unsigned short h=f2bf(v);
      s_eeh[idx]=h; s_eel[idx]=f2bf(v-bf2f(h));
    }
    __syncthreads();
    for (int f=0; f<ncur; f++){
      int kt=c+f;
      bf16x8 Ah=*(const bf16x8*)(s_eeh + f*512 + lane*8);
      bf16x8 Al=*(const bf16x8*)(s_eel + f*512 + lane*8);
      size_t ba=(size_t)(kt*8+nta)*512+lane*8;
      {
        bf16x8 Bh=*(const bf16x8*)(r1h+ba), Bl=*(const bf16x8*)(r1l+ba);
        bf16x8 Bh2=*(const bf16x8*)(r1h+ba+512), Bl2=*(const bf16x8*)(r1l+ba+512);
        aR0=__builtin_amdgcn_mfma_f32_16x16x32_bf16(Ah,Bh,aR0,0,0,0);
        aR0=__builtin_amdgcn_mfma_f32_16x16x32_bf16(Al,Bh,aR0,0,0,0);
        aR0=__builtin_amdgcn_mfma_f32_16x16x32_bf16(Ah,Bl,aR0,0,0,0);
        aR1=__builtin_amdgcn_mfma_f32_16x16x32_bf16(Ah,Bh2,aR1,0,0,0);
        aR1=__builtin_amdgcn_mfma_f32_16x16x32_bf16(Al,Bh2,aR1,0,0,0);
        aR1=__builtin_amdgcn_mfma_f32_16x16x32_bf16(Ah,Bl2,aR1,0,0,0);
      }
      if (do_deg){
        bf16x8 Bh=*(const bf16x8*)(dw1h+ba), Bl=*(const bf16x8*)(dw1l+ba);
        bf16x8 Bh2=*(const bf16x8*)(dw1h+ba+512), Bl2=*(const bf16x8*)(dw1l+ba+512);
        aD0=__builtin_amdgcn_mfma_f32_16x16x32_bf16(Ah,Bh,aD0,0,0,0);
        aD0=__builtin_amdgcn_mfma_f32_16x16x32_bf16(Al,Bh,aD0,0,0,0);
        aD0=__builtin_amdgcn_mfma_f32_16x16x32_bf16(Ah,Bl,aD0,0,0,0);
        aD1=__builtin_amdgcn_mfma_f32_16x16x32_bf16(Ah,Bh2,aD1,0,0,0);
        aD1=__builtin_amdgcn_mfma_f32_16x16x32_bf16(Al,Bh2,aD1,0,0,0);
        aD1=__builtin_amdgcn_mfma_f32_16x16x32_bf16(Ah,Bl2,aD1,0,0,0);
      }
    }
    __syncthreads();
  }
  int nmlp = do_deg ? 2 : 1;
  #pragma unroll 1
  for (int it=0; it<nmlp; it++){
    int is_deg = (it==1);
    f32x4 a0 = is_deg ? aD0 : aR0;
    f32x4 a1 = is_deg ? aD1 : aR1;
    const float* b1 = is_deg ? db1 : rb1;
    #pragma unroll
    for (int q=0;q<4;q++){
      int row=khi*4+q;
      {
        int col=nta*16+lanelo;
        float v=silu_f(a0[q]+b1[col]);
        int pos=row*128 + (((col>>3)^(row&7))<<3) + (col&7);
        unsigned short h=f2bf(v);
        s_h1h[pos]=h; s_h1l[pos]=f2bf(v-bf2f(h));
      }
      {
        int col=ntb*16+lanelo;
        float v=silu_f(a1[q]+b1[col]);
        int pos=row*128 + (((col>>3)^(row&7))<<3) + (col&7);
        unsigned short h=f2bf(v);
        s_h1h[pos]=h; s_h1l[pos]=f2bf(v-bf2f(h));
      }
    }
    __syncthreads();
    bf16x8 Ahh[4],Ahl[4];
    #pragma unroll
    for (int kt=0;kt<4;kt++){
      int o=lanelo*128 + (((kt*4+khi)^(lanelo&7))<<3);
      Ahh[kt]=*(const bf16x8*)(s_h1h+o);
      Ahl[kt]=*(const bf16x8*)(s_h1l+o);
    }
    __syncthreads();
    if (is_deg){
      for (int nt=wv; nt<76; nt+=4){
        f32x4 acc=z4;
        #pragma unroll
        for (int kt=0;kt<4;kt++){
          size_t bo=(size_t)(kt*76+nt)*512+lane*8;
          bf16x8 Bh=*(const bf16x8*)(dw2h+bo), Bl=*(const bf16x8*)(dw2l+bo);
          acc=__builtin_amdgcn_mfma_f32_16x16x32_bf16(Ahh[kt],Bh,acc,0,0,0);
          acc=__builtin_amdgcn_mfma_f32_16x16x32_bf16(Ahl[kt],Bh,acc,0,0,0);
          acc=__builtin_amdgcn_mfma_f32_16x16x32_bf16(Ahh[kt],Bl,acc,0,0,0);
        }
        int col=nt*16+lanelo;
        float bb2=db2[col];
        #pragma unroll
        for (int q=0;q<4;q++){
          int p=p0+khi*4+q;
          if (p<E) degout[(size_t)p*1216+col]=f2bf(acc[q]+bb2);
        }
      }
    } else {
      for (int nt=wv; nt<24; nt+=4){
        f32x4 acc=z4;
        #pragma unroll
        for (int kt=0;kt<4;kt++){
          size_t bo=(size_t)(kt*24+nt)*512+lane*8;
          bf16x8 Bh=*(const bf16x8*)(r2h+bo), Bl=*(const bf16x8*)(r2l+bo);
          acc=__builtin_amdgcn_mfma_f32_16x16x32_bf16(Ahh[kt],Bh,acc,0,0,0);
          acc=__builtin_amdgcn_mfma_f32_16x16x32_bf16(Ahl[kt],Bh,acc,0,0,0);
          acc=__builtin_amdgcn_mfma_f32_16x16x32_bf16(Ahh[kt],Bl,acc,0,0,0);
        }
        int col=nt*16+lanelo;
        float bb2=rb2[col];
        #pragma unroll
        for (int q=0;q<4;q++){
          int e=s_e[khi*4+q];
          if (e>=0) radout[(size_t)e*384+col]=f2bf(acc[q]+bb2);
        }
      }
    }
  }
}

// ---------------- wave-per-edge node gather + prefetch + fused rms-norm + mx/den init -----
// mode 0: x += sum, oe strided (attn layout), xn = norm(x)*nw.
// mode 1: x = base + 0.05*sum, oe contiguous (deg layout), xn = norm(x)*nw.
__global__ __launch_bounds__(256) void node_sum_kernel(const unsigned short* __restrict__ msgb,
    const float* __restrict__ winv, const int* __restrict__ rowptr, const int* __restrict__ eix,
    const int* __restrict__ nsp, const float* __restrict__ spe,
    const float* __restrict__ nw, float* __restrict__ x, float* __restrict__ xn,
    float* __restrict__ mx, float* __restrict__ den,
    int mode, int N){
  int n=blockIdx.x, tid=threadIdx.x, wv=tid>>6, lane=tid&63;
  __shared__ float s_winv[4][480];
  __shared__ unsigned short s_oe[4][1216];
  __shared__ float4 s_red[4][400];
  __shared__ float4 s_ms4[16];
  if (tid<8){ mx[n*8+tid]=-3.0e38f; den[n*8+tid]=0.0f; }   // init for the NEXT msg pass
  int row0=rowptr[n];
  int cnt=rowptr[n+1]-row0;
  float4 acc[7];
  #pragma unroll
  for (int t=0;t<7;t++) acc[t]=make_float4(0,0,0,0);
  float wpre[8];
  int4 opre[3];
  int j=wv;
  if (j<cnt){
    int p=row0+j;
    int e=eix[p];
    #pragma unroll
    for (int t=0;t<8;t++){ int k=lane+t*64; wpre[t]=(k<475)? winv[(size_t)e*475+k] : 0.0f; }
    if (mode==1){
      #pragma unroll
      for (int t=0;t<3;t++){
        int k=lane+t*64;
        opre[t]=(k<152)? *(const int4*)(msgb+(size_t)p*1216+(size_t)k*8) : make_int4(0,0,0,0);
      }
    } else {
      #pragma unroll
      for (int t=0;t<3;t++){
        int k=lane+t*64;
        if (k<152){ int m=k>>3, jj=k&7; opre[t]=*(const int4*)(msgb+(size_t)p*2432+m*128+jj*8); }
        else opre[t]=make_int4(0,0,0,0);
      }
    }
  }
  for (; j<cnt; j+=4){
    asm volatile("s_waitcnt lgkmcnt(0)" ::: "memory");
    #pragma unroll
    for (int t=0;t<8;t++){ int k=lane+t*64; if (k<475) s_winv[wv][k]=wpre[t]; }
    #pragma unroll
    for (int t=0;t<3;t++){ int k=lane+t*64; if (k<152) ((int4*)s_oe[wv])[k]=opre[t]; }
    int jn=j+4;
    if (jn<cnt){
      int p=row0+jn;
      int e=eix[p];
      #pragma unroll
      for (int t=0;t<8;t++){ int k=lane+t*64; wpre[t]=(k<475)? winv[(size_t)e*475+k] : 0.0f; }
      if (mode==1){
        #pragma unroll
        for (int t=0;t<3;t++){
          int k=lane+t*64;
          opre[t]=(k<152)? *(const int4*)(msgb+(size_t)p*1216+(size_t)k*8) : make_int4(0,0,0,0);
        }
      } else {
        #pragma unroll
        for (int t=0;t<3;t++){
          int k=lane+t*64;
          if (k<152){ int m=k>>3, jj=k&7; opre[t]=*(const int4*)(msgb+(size_t)p*2432+m*128+jj*8); }
          else opre[t]=make_int4(0,0,0,0);
        }
      }
    }
    asm volatile("s_waitcnt lgkmcnt(0)" ::: "memory");
    const unsigned* o2=(const unsigned*)s_oe[wv];
    #pragma unroll
    for (int t=0;t<7;t++){
      int sI=lane+t*64;
      if (sI<400){
        int l=sI>>4, c4=sI&15;
        const float* wr=s_winv[wv]+l*19;
        float4 a=acc[t];
        #pragma unroll
        for (int m=0;m<19;m++){
          float w=wr[m];
          unsigned ua=o2[m*32+c4*2], ub=o2[m*32+c4*2+1];
          a.x+=w*bf2f((unsigned short)(ua&0xffffu));
          a.y+=w*bf2f((unsigned short)(ua>>16));
          a.z+=w*bf2f((unsigned short)(ub&0xffffu));
          a.w+=w*bf2f((unsigned short)(ub>>16));
        }
        acc[t]=a;
      }
    }
  }
  asm volatile("s_waitcnt lgkmcnt(0)" ::: "memory");
  #pragma unroll
  for (int t=0;t<7;t++){
    int sI=lane+t*64;
    if (sI<400) s_red[wv][sI]=acc[t];
  }
  __syncthreads();
  float4* xp=(float4*)(x+(size_t)n*1600);
  int j0=tid, j1=tid+256;
  bool h1=(j1<400);
  float4 v0, v1=make_float4(0,0,0,0);
  if (mode==0){
    {
      float4 a=s_red[0][j0], b=s_red[1][j0], c=s_red[2][j0], d=s_red[3][j0];
      float4 cur=xp[j0];
      cur.x+=a.x+b.x+c.x+d.x;
      cur.y+=a.y+b.y+c.y+d.y;
      cur.z+=a.z+b.z+c.z+d.z;
      cur.w+=a.w+b.w+c.w+d.w;
      v0=cur; xp[j0]=cur;
    }
    if (h1){
      float4 a=s_red[0][j1], b=s_red[1][j1], c=s_red[2][j1], d=s_red[3][j1];
      float4 cur=xp[j1];
      cur.x+=a.x+b.x+c.x+d.x;
      cur.y+=a.y+b.y+c.y+d.y;
      cur.z+=a.z+b.z+c.z+d.z;
      cur.w+=a.w+b.w+c.w+d.w;
      v1=cur; xp[j1]=cur;
    }
  } else {
    int sp=nsp[n];
    const float4* sp4=(const float4*)(spe+(size_t)sp*64);
    {
      int l=j0>>4, c4=j0&15;
      float4 a=s_red[0][j0], b=s_red[1][j0], c=s_red[2][j0], d=s_red[3][j0];
      float4 base=(l==0)? sp4[c4] : make_float4(0,0,0,0);
      float4 o;
      o.x=base.x+0.05f*(a.x+b.x+c.x+d.x);
      o.y=base.y+0.05f*(a.y+b.y+c.y+d.y);
      o.z=base.z+0.05f*(a.z+b.z+c.z+d.z);
      o.w=base.w+0.05f*(a.w+b.w+c.w+d.w);
      v0=o; xp[j0]=o;
    }
    if (h1){
      float4 a=s_red[0][j1], b=s_red[1][j1], c=s_red[2][j1], d=s_red[3][j1];
      float4 o;
      o.x=0.05f*(a.x+b.x+c.x+d.x);
      o.y=0.05f*(a.y+b.y+c.y+d.y);
      o.z=0.05f*(a.z+b.z+c.z+d.z);
      o.w=0.05f*(a.w+b.w+c.w+d.w);
      v1=o; xp[j1]=o;
    }
  }
  __syncthreads();   // all s_red reads done -> safe to alias as partial buffer
  float4* s_p4=(float4*)s_red;
  float4 a4;
  a4.x=v0.x*v0.x; a4.y=v0.y*v0.y; a4.z=v0.z*v0.z; a4.w=v0.w*v0.w;
  if (h1){ a4.x+=v1.x*v1.x; a4.y+=v1.y*v1.y; a4.z+=v1.z*v1.z; a4.w+=v1.w*v1.w; }
  s_p4[tid]=a4;
  __syncthreads();
  if (tid<16){
    float4 s=make_float4(0,0,0,0);
    #pragma unroll
    for (int k=0;k<16;k++){
      float4 p=s_p4[tid+16*k];
      s.x+=p.x; s.y+=p.y; s.z+=p.z; s.w+=p.w;
    }
    float4 m;
    m.x=rsqrtf(s.x*(1.0f/25.0f)+1e-6f);
    m.y=rsqrtf(s.y*(1.0f/25.0f)+1e-6f);
    m.z=rsqrtf(s.z*(1.0f/25.0f)+1e-6f);
    m.w=rsqrtf(s.w*(1.0f/25.0f)+1e-6f);
    s_ms4[tid]=m;
  }
  __syncthreads();
  float4* xnp=(float4*)(xn+(size_t)n*1600);
  {
    int l=j0>>4, g=j0&15;
    float4 m=s_ms4[g];
    const float* wr=nw + d_loc[l]*64 + g*4;
    float4 o;
    o.x=v0.x*m.x*wr[0]; o.y=v0.y*m.y*wr[1]; o.z=v0.z*m.z*wr[2]; o.w=v0.w*m.w*wr[3];
    xnp[j0]=o;
  }
  if (h1){
    int l=j1>>4, g=j1&15;
    float4 m=s_ms4[g];
    const float* wr=nw + d_loc[l]*64 + g*4;
    float4 o;
    o.x=v1.x*m.x*wr[0]; o.y=v1.y*m.y*wr[1]; o.z=v1.z*m.z*wr[2]; o.w=v1.w*m.w*wr[3];
    xnp[j1]=o;
  }
}

__global__ __launch_bounds__(256) void den_kernel(const float* __restrict__ logits,
    const float* __restrict__ mx, const int* __restrict__ rcv,
    float* __restrict__ den, int E){
  int idx = blockIdx.x*256+threadIdx.x;
  if (idx >= E*8) return;
  int e = idx>>3, hd = idx&7, r = rcv[e];
  atomicAdd(&den[r*8+hd], __expf(logits[idx]-mx[r*8+hd]));
}

// ---------------- pass 2a: msg + fused alpha-logits, wave-per-edge (4 edges/block) -----------
// rad read as bf16.
__global__ __launch_bounds__(256) void msg_kernel(const float* __restrict__ xn,
    const float* __restrict__ wig, const unsigned short* __restrict__ radb,
    const float* __restrict__ so2W, const float* __restrict__ alphaW, const float* __restrict__ alphaV,
    const int* __restrict__ snd, const int* __restrict__ rcv, const int* __restrict__ eix,
    unsigned short* __restrict__ msgb, float* __restrict__ logits, float* __restrict__ mx, int E){
  __shared__ float s_wig[1900];   // 4 waves x 475
  __shared__ float s_m0[4][128];
  __shared__ float s_sh0[4][64];
  int tid=threadIdx.x, wv=tid>>6, lane=tid&63;
  int p=blockIdx.x*4+wv;
  bool act=(p<E);
  int pc=act? p : (E-1);
  int e=eix[pc];
  int node=(lane<32)? snd[e] : rcv[e];
  int c2=(lane&31)*2;
  int col0=c2+((lane>>5)<<6);   // global col, even
  const float* xb=xn+(size_t)node*1600+c2;
  float ca[25], cb[25];
  #pragma unroll
  for (int l=0;l<25;l++){
    float2 v=*(const float2*)(xb+l*64);
    ca[l]=v.x; cb[l]=v.y;
  }
  float* swig=s_wig+wv*475;
  for (int j=lane;j<475;j+=64) swig[j]=wig[(size_t)e*475+j];
  float ra0,ra1,rb0,rb1,rc0,rc1;
  {
    const unsigned short* rb_=radb+(size_t)e*384;
    unsigned u0=*(const unsigned*)(rb_+col0);
    unsigned u1=*(const unsigned*)(rb_+128+col0);
    unsigned u2=*(const unsigned*)(rb_+256+col0);
    ra0=bf2f((unsigned short)(u0&0xffffu)); ra1=bf2f((unsigned short)(u0>>16));
    rb0=bf2f((unsigned short)(u1&0xffffu)); rb1=bf2f((unsigned short)(u1>>16));
    rc0=bf2f((unsigned short)(u2&0xffffu)); rc1=bf2f((unsigned short)(u2>>16));
  }
  __syncthreads();
  unsigned short* dst=msgb+(size_t)pc*2432+col0;
  constexpr int mgc[19]={0,1,0,1,2,1,0,1,2,2,1,0,1,2,2,1,0,1,2};
  float m0a=0.0f, m0b=0.0f;
  if (act){
    #pragma unroll
    for (int m=0;m<19;m++){
      float a0=0.0f,a1=0.0f;
      const float* wr=swig+m*25;
      #pragma unroll
      for (int l=0;l<25;l++){ float w=wr[l]; a0+=w*ca[l]; a1+=w*cb[l]; }
      float r0,r1;
      if (mgc[m]==0){ r0=ra0; r1=ra1; }
      else if (mgc[m]==1){ r0=rb0; r1=rb1; }
      else { r0=rc0; r1=rc1; }
      a0*=r0; a1*=r1;
      if (m==0){ m0a=a0; m0b=a1; }
      unsigned packv=((unsigned)f2bf(a1)<<16)|(unsigned)f2bf(a0);
      *(unsigned*)(dst+m*128)=packv;
    }
  }
  // ---- fused alpha-logits chain (wave-local; inactive waves compute garbage, writes guarded)
  s_m0[wv][col0]=m0a; s_m0[wv][col0+1]=m0b;
  asm volatile("s_waitcnt lgkmcnt(0)" ::: "memory");
  {
    const float* m0p=s_m0[wv];
    float accs=0.0f;
    #pragma unroll 8
    for (int k=0;k<128;k++) accs += m0p[k]*so2W[k*64+lane];
    s_sh0[wv][lane]=silu_f(accs);
  }
  asm volatile("s_waitcnt lgkmcnt(0)" ::: "memory");
  {
    const float* sh=s_sh0[wv];
    int j0=lane*4;
    float4 av=*(const float4*)(alphaV+j0);
    float4 aacc={0,0,0,0};
    #pragma unroll 8
    for (int o=0;o<64;o++){
      float s=sh[o];
      float4 w=*(const float4*)(alphaW+o*256+j0);
      aacc.x+=s*w.x; aacc.y+=s*w.y; aacc.z+=s*w.z; aacc.w+=s*w.w;
    }
    float part = silu_f(aacc.x)*av.x + silu_f(aacc.y)*av.y
               + silu_f(aacc.z)*av.z + silu_f(aacc.w)*av.w;
    part += __shfl_xor(part,1);
    part += __shfl_xor(part,2);
    part += __shfl_xor(part,4);
    if (act && (lane&7)==0){
      int h=lane>>3;
      int r=rcv[e];
      logits[(size_t)e*8+h]=part;
      atomicMaxF(&mx[r*8+h], part);
    }
  }
}

// ---------------- pass 2b: 16-edge MFMA GEMM: vv = msg@wsv (*attn), oe = vv@proj ----------------
__global__ __launch_bounds__(256) void attn_gemm_kernel(unsigned short* __restrict__ msgb,
    const unsigned short* __restrict__ wsvp, const unsigned short* __restrict__ projp,
    const float* __restrict__ logits, const float* __restrict__ mx, const float* __restrict__ den,
    const int* __restrict__ eix, const int* __restrict__ rcv, int E){
  int tid=threadIdx.x, wv=tid>>6, lane=tid&63;
  int lanelo=lane&15, khi=lane>>4;
  int p0=blockIdx.x*16;
  __shared__ unsigned short s_vv[2176];   // [16][136]
  __shared__ float s_attn[16][8];
  __shared__ short s_r2e[304], s_r2m[304];
  for (int j=tid;j<304;j+=256){
    int e,m;
    if (j<80){ e=j/5; m=d_mg0[j%5]; }
    else if (j<208){ int q=j-80; e=q>>3; m=d_mg1[q&7]; }
    else { int q=j-208; e=q/6; m=d_mg2[q%6]; }
    s_r2e[j]=(short)e; s_r2m[j]=(short)m;
  }
  if (tid<128){
    int i=tid>>3, h=tid&7, p=p0+i;
    float a=0.0f;
    if (p<E){
      int e=eix[p]; int r=rcv[e];
      a=__expf(logits[(size_t)e*8+h]-mx[r*8+h])/(den[r*8+h]+1e-12f);
    }
    s_attn[i][h]=a;
  }
  __syncthreads();
  const int4* wp4=(const int4*)wsvp;
  const int4* pp4=(const int4*)projp;
  for (int t=0;t<19;t++){
    int g=(t<5)?0:((t<13)?1:2);
    int R=t*16+lanelo;
    int ei=s_r2e[R], mi=s_r2m[R];
    int pp=p0+ei;
    size_t abase=((size_t)((pp<E)?pp:0))*2432 + (size_t)mi*128;
    bf16x8 A[4];
    #pragma unroll
    for (int kt=0;kt<4;kt++)
      A[kt]=*(const bf16x8*)(msgb + abase + kt*32 + khi*8);
    #pragma unroll
    for (int h2=0;h2<2;h2++){
      int nt=wv*2+h2;
      f32x4 acc={0,0,0,0};
      #pragma unroll
      for (int kt=0;kt<4;kt++){
        int4 tt=wp4[g*2048+(kt*8+nt)*64+lane];
        acc=__builtin_amdgcn_mfma_f32_16x16x32_bf16(A[kt],*(bf16x8*)&tt,acc,0,0,0);
      }
      int col=nt*16+lanelo;
      #pragma unroll
      for (int q=0;q<4;q++){
        int r16=khi*4+q;
        int ei2=s_r2e[t*16+r16];
        s_vv[r16*136+col]=f2bf(acc[q]*s_attn[ei2][nt]);
      }
    }
    __syncthreads();
    {
      bf16x8 A2[4];
      #pragma unroll
      for (int kt=0;kt<4;kt++)
        A2[kt]=*(const bf16x8*)(s_vv + lanelo*136 + kt*32 + khi*8);
      f32x4 acc={0,0,0,0};
      #pragma unroll
      for (int kt=0;kt<4;kt++){
        int4 tt=pp4[g*1024+(kt*4+wv)*64+lane];
        acc=__builtin_amdgcn_mfma_f32_16x16x32_bf16(A2[kt],*(bf16x8*)&tt,acc,0,0,0);
      }
      int col=wv*16+lanelo;
      #pragma unroll
      for (int q=0;q<4;q++){
        int R2=t*16+khi*4+q;
        int pi=p0+s_r2e[R2];
        if (pi<E) msgb[(size_t)pi*2432 + (size_t)s_r2m[R2]*128 + col]=f2bf(acc[q]);
      }
    }
    __syncthreads();
  }
}

// ---------------- S2 grid FFN via split-bf16 MFMA + FUSED next-layer rms-norm -------------
__global__ __launch_bounds__(256) void grid_ffn_mfma_kernel(const float* __restrict__ xnin,
    const unsigned short* __restrict__ tgp, const unsigned short* __restrict__ fgp,
    const unsigned short* __restrict__ w1p, const unsigned short* __restrict__ w2p,
    const float* __restrict__ b1, const float* __restrict__ nw,
    float* __restrict__ x, float* __restrict__ xnout, int N){
  int n=blockIdx.x, tid=threadIdx.x, wv=tid>>6, lane=tid&63;
  int lanelo=lane&15, khi=lane>>4;
  __shared__ __align__(16) char s_mem[74240];
  unsigned short* s_w1=(unsigned short*)s_mem;             // hi 8192 | lo 8192 shorts (32KB)
  unsigned short* s_xn=(unsigned short*)(s_mem+32768);     // hi 2048 | lo 2048 shorts (8KB)
  float* s_b1=(float*)(s_mem+40960);                       // 128 f
  unsigned short* scr=(unsigned short*)(s_mem+41472)+(size_t)wv*4096;  // 8KB/wave
  for (int j=tid;j<2048;j+=256) ((int4*)s_w1)[j]=((const int4*)w1p)[j];
  if (tid<128) s_b1[tid]=b1[tid];
  { int4 z={0,0,0,0}; for (int j=tid;j<512;j+=256) ((int4*)s_xn)[j]=z; }
  __syncthreads();
  {
    const float* xr=xnin+(size_t)n*1600;
    for (int j=tid;j<1600;j+=256){
      int k=j>>6, c=j&63;
      float v=xr[j];
      unsigned short h=f2bf(v);
      s_xn[c*32+k]=h;
      s_xn[2048+c*32+k]=f2bf(v-bf2f(h));
    }
  }
  __syncthreads();
  bf16x8 XBh[4],XBl[4];
  #pragma unroll
  for (int ct=0;ct<4;ct++){
    int o=(ct*16+lanelo)*32 + khi*8;
    XBh[ct]=*(const bf16x8*)(s_xn+o);
    XBl[ct]=*(const bf16x8*)(s_xn+2048+o);
  }
  f32x4 oacc[2][4];
  #pragma unroll
  for (int mt=0;mt<2;mt++)
    #pragma unroll
    for (int nt=0;nt<4;nt++){ f32x4 z={0,0,0,0}; oacc[mt][nt]=z; }
  for (int t=wv;t<18;t+=4){
    bf16x8 Atgh=*(const bf16x8*)(tgp + t*512 + lane*8);
    bf16x8 Atgl=*(const bf16x8*)(tgp + 9216 + t*512 + lane*8);
    #pragma unroll
    for (int ct=0;ct<4;ct++){
      f32x4 g={0,0,0,0};
      g=__builtin_amdgcn_mfma_f32_16x16x32_bf16(Atgh,XBh[ct],g,0,0,0);
      g=__builtin_amdgcn_mfma_f32_16x16x32_bf16(Atgl,XBh[ct],g,0,0,0);
      g=__builtin_amdgcn_mfma_f32_16x16x32_bf16(Atgh,XBl[ct],g,0,0,0);
      #pragma unroll
      for (int q=0;q<4;q++){
        int row=khi*4+q, col=ct*16+lanelo;
        int pos=row*64 + (((col>>3)^(row&7))<<3) + (col&7);
        float v=g[q]; unsigned short h=f2bf(v);
        scr[pos]=h; scr[1024+pos]=f2bf(v-bf2f(h));
      }
    }
    bf16x8 Agh[2],Agl[2];
    #pragma unroll
    for (int kt=0;kt<2;kt++){
      int o=lanelo*64 + (((kt*4+khi)^(lanelo&7))<<3);
      Agh[kt]=*(const bf16x8*)(scr+o);
      Agl[kt]=*(const bf16x8*)(scr+1024+o);
    }
    #pragma unroll
    for (int nt=0;nt<8;nt++){
      f32x4 h={0,0,0,0};
      #pragma unroll
      for (int kt=0;kt<2;kt++){
        bf16x8 Bh=*(const bf16x8*)(s_w1 + (kt*8+nt)*512 + lane*8);
        bf16x8 Bl=*(const bf16x8*)(s_w1 + 8192 + (kt*8+nt)*512 + lane*8);
        h=__builtin_amdgcn_mfma_f32_16x16x32_bf16(Agh[kt],Bh,h,0,0,0);
        h=__builtin_amdgcn_mfma_f32_16x16x32_bf16(Agl[kt],Bh,h,0,0,0);
        h=__builtin_amdgcn_mfma_f32_16x16x32_bf16(Agh[kt],Bl,h,0,0,0);
      }
      #pragma unroll
      for (int q=0;q<4;q++){
        int row=khi*4+q, col=nt*16+lanelo;
        float v=silu_f(h[q]+s_b1[col]);
        int pos=row*128 + (((col>>3)^(row&7))<<3) + (col&7);
        unsigned short hh=f2bf(v);
        scr[pos]=hh; scr[2048+pos]=f2bf(v-bf2f(hh));
      }
    }
    bf16x8 Ahh[4],Ahl[4];
    #pragma unroll
    for (int kt=0;kt<4;kt++){
      int o=lanelo*128 + (((kt*4+khi)^(lanelo&7))<<3);
      Ahh[kt]=*(const bf16x8*)(scr+o);
      Ahl[kt]=*(const bf16x8*)(scr+2048+o);
    }
    #pragma unroll
    for (int nt=0;nt<4;nt++){
      f32x4 o4={0,0,0,0};
      #pragma unroll
      for (int kt=0;kt<4;kt++){
        bf16x8 Bh=*(const bf16x8*)(w2p + (kt*4+nt)*512 + lane*8);
        bf16x8 Bl=*(const bf16x8*)(w2p + 8192 + (kt*4+nt)*512 + lane*8);
        o4=__builtin_amdgcn_mfma_f32_16x16x32_bf16(Ahh[kt],Bh,o4,0,0,0);
        o4=__builtin_amdgcn_mfma_f32_16x16x32_bf16(Ahl[kt],Bh,o4,0,0,0);
        o4=__builtin_amdgcn_mfma_f32_16x16x32_bf16(Ahh[kt],Bl,o4,0,0,0);
      }
      #pragma unroll
      for (int q=0;q<4;q++){
        int ch=nt*16+lanelo, rowk=khi*4+q;
        int pos=ch*32 + (((rowk>>3)^(ch&3))<<3) + (rowk&7);
        float v=o4[q]; unsigned short hh=f2bf(v);
        scr[pos]=hh; scr[2048+pos]=f2bf(v-bf2f(hh));
      }
    }
    bf16x8 Boh[4],Bol[4];
    #pragma unroll
    for (int nt=0;nt<4;nt++){
      int ch=nt*16+lanelo;
      int o=ch*32 + ((khi^(ch&3))<<3);
      Boh[nt]=*(const bf16x8*)(scr+o);
      Bol[nt]=*(const bf16x8*)(scr+2048+o);
    }
    #pragma unroll
    for (int mt=0;mt<2;mt++){
      bf16x8 Afh=*(const bf16x8*)(fgp + (t*2+mt)*512 + lane*8);
      bf16x8 Afl=*(const bf16x8*)(fgp + 18432 + (t*2+mt)*512 + lane*8);
      #pragma unroll
      for (int nt=0;nt<4;nt++){
        oacc[mt][nt]=__builtin_amdgcn_mfma_f32_16x16x32_bf16(Afh,Boh[nt],oacc[mt][nt],0,0,0);
        oacc[mt][nt]=__builtin_amdgcn_mfma_f32_16x16x32_bf16(Afl,Boh[nt],oacc[mt][nt],0,0,0);
        oacc[mt][nt]=__builtin_amdgcn_mfma_f32_16x16x32_bf16(Afh,Bol[nt],oacc[mt][nt],0,0,0);
      }
    }
  }
  __syncthreads();
  float* pout=(float*)s_mem;   // alias W1 region: 4 waves x [32][64] fp32 (32KB)
  #pragma unroll
  for (int mt=0;mt<2;mt++)
    #pragma unroll
    for (int nt=0;nt<4;nt++)
      #pragma unroll
      for (int q=0;q<4;q++){
        int row=mt*16+khi*4+q, col=nt*16+lanelo;
        pout[wv*2048 + row*64 + col]=oacc[mt][nt][q];
      }
  __syncthreads();
  const size_t nb=(size_t)n*1600;
  float accn=0.0f;
  for (int j=tid;j<1600;j+=256){
    float v = x[nb+j] + pout[j]+pout[2048+j]+pout[4096+j]+pout[6144+j];
    x[nb+j]=v;
    accn += v*v;
  }
  __syncthreads();   // pout reads done -> safe to alias
  float* s_part=(float*)s_mem;
  float* s_msv=((float*)s_mem)+256;
  s_part[tid]=accn;
  __syncthreads();
  if (tid<64){
    float m=(s_part[tid]+s_part[tid+64]+s_part[tid+128]+s_part[tid+192])*(1.0f/25.0f);
    s_msv[tid]=rsqrtf(m+1e-6f);
  }
  __syncthreads();
  for (int j=tid;j<1600;j+=256){
    int l=j>>6, c=j&63;
    xnout[nb+j]=x[nb+j]*s_msv[c]*nw[d_loc[l]*64+c];
  }
}

// ---------------- final energy head via split-bf16 MFMA ----------------
__global__ __launch_bounds__(256) void energy_mfma_kernel(const float* __restrict__ xn,
    const unsigned short* __restrict__ tgp, const float* __restrict__ fg,
    const unsigned short* __restrict__ enw1p, const float* __restrict__ b1,
    const float* __restrict__ w2, const float* __restrict__ b2,
    float* __restrict__ out, int N){
  int n=blockIdx.x, tid=threadIdx.x, wv=tid>>6, lane=tid&63;
  int lanelo=lane&15, khi=lane>>4;
  __shared__ __align__(16) char s_mem[59584];
  unsigned short* s_w1=(unsigned short*)s_mem;             // hi 8192 | lo 8192 shorts
  unsigned short* s_xn=(unsigned short*)(s_mem+32768);     // hi 2048 | lo 2048
  float* s_b1=(float*)(s_mem+40960);
  float* s_w2=(float*)(s_mem+41472);
  float* s_fg0=(float*)(s_mem+41984);                      // 288 f
  float* s_red=(float*)(s_mem+43136);
  unsigned short* scr=(unsigned short*)(s_mem+43200)+(size_t)wv*2048;  // 4KB/wave (g hi|lo)
  for (int j=tid;j<2048;j+=256) ((int4*)s_w1)[j]=((const int4*)enw1p)[j];
  if (tid<128){ s_b1[tid]=b1[tid]; s_w2[tid]=w2[tid]; }
  for (int j=tid;j<288;j+=256) s_fg0[j]=fg[j];
  { int4 z={0,0,0,0}; for (int j=tid;j<512;j+=256) ((int4*)s_xn)[j]=z; }
  __syncthreads();
  {
    const float* xr=xn+(size_t)n*1600;
    for (int j=tid;j<1600;j+=256){
      int k=j>>6, c=j&63;
      float v=xr[j];
      unsigned short h=f2bf(v);
      s_xn[c*32+k]=h;
      s_xn[2048+c*32+k]=f2bf(v-bf2f(h));
    }
  }
  __syncthreads();
  bf16x8 XBh[4],XBl[4];
  #pragma unroll
  for (int ct=0;ct<4;ct++){
    int o=(ct*16+lanelo)*32 + khi*8;
    XBh[ct]=*(const bf16x8*)(s_xn+o);
    XBl[ct]=*(const bf16x8*)(s_xn+2048+o);
  }
  float b2v=b2[0];
  float e=0.0f;
  for (int t=wv;t<18;t+=4){
    bf16x8 Atgh=*(const bf16x8*)(tgp + t*512 + lane*8);
    bf16x8 Atgl=*(const bf16x8*)(tgp + 9216 + t*512 + lane*8);
    #pragma unroll
    for (int ct=0;ct<4;ct++){
      f32x4 g={0,0,0,0};
      g=__builtin_amdgcn_mfma_f32_16x16x32_bf16(Atgh,XBh[ct],g,0,0,0);
      g=__builtin_amdgcn_mfma_f32_16x16x32_bf16(Atgl,XBh[ct],g,0,0,0);
      g=__builtin_amdgcn_mfma_f32_16x16x32_bf16(Atgh,XBl[ct],g,0,0,0);
      #pragma unroll
      for (int q=0;q<4;q++){
        int row=khi*4+q, col=ct*16+lanelo;
        int pos=row*64 + (((col>>3)^(row&7))<<3) + (col&7);
        float v=g[q]; unsigned short h=f2bf(v);
        scr[pos]=h; scr[1024+pos]=f2bf(v-bf2f(h));
      }
    }
    bf16x8 Agh[2],Agl[2];
    #pragma unroll
    for (int kt=0;kt<2;kt++){
      int o=lanelo*64 + (((kt*4+khi)^(lanelo&7))<<3);
      Agh[kt]=*(const bf16x8*)(scr+o);
      Agl[kt]=*(const bf16x8*)(scr+1024+o);
    }
    #pragma unroll
    for (int nt=0;nt<8;nt++){
      f32x4 h={0,0,0,0};
      #pragma unroll
      for (int kt=0;kt<2;kt++){
        bf16x8 Bh=*(const bf16x8*)(s_w1 + (kt*8+nt)*512 + lane*8);
        bf16x8 Bl=*(const bf16x8*)(s_w1 + 8192 + (kt*8+nt)*512 + lane*8);
        h=__builtin_amdgcn_mfma_f32_16x16x32_bf16(Agh[kt],Bh,h,0,0,0);
        h=__builtin_amdgcn_mfma_f32_16x16x32_bf16(Agl[kt],Bh,h,0,0,0);
        h=__builtin_amdgcn_mfma_f32_16x16x32_bf16(Agh[kt],Bl,h,0,0,0);
      }
      #pragma unroll
      for (int q=0;q<4;q++){
        int row=khi*4+q, col=nt*16+lanelo;
        float v=silu_f(h[q]+s_b1[col]);
        e += v*s_w2[col]*s_fg0[t*16+row];
      }
    }
    if (lanelo==0){
      #pragma unroll
      for (int q=0;q<4;q++) e += s_fg0[t*16+khi*4+q]*b2v;
    }
  }
  #pragma unroll
  for (int d=1;d<64;d<<=1) e += __shfl_xor(e,d);
  if (lane==0) s_red[wv]=e;
  __syncthreads();
  if (tid==0) out[n]=(s_red[0]+s_red[1]+s_red[2]+s_red[3])*(1.0f/2000.0f);
}

extern "C" void kernel_launch(void* const* d_in, const int* in_sizes, int n_in,
                              void* d_out, int out_size, void* d_ws, size_t ws_size,
                              hipStream_t stream){
  (void)n_in; (void)out_size; (void)ws_size;
  const float* ev   = (const float*)d_in[0];
  const float* wig  = (const float*)d_in[1];
  const float* winv = (const float*)d_in[2];
  const float* spe  = (const float*)d_in[3];
  const float* ese  = (const float*)d_in[4];
  const float* degW1= (const float*)d_in[5];
  const float* degb1= (const float*)d_in[6];
  const float* degW2= (const float*)d_in[7];
  const float* degb2= (const float*)d_in[8];
  const float* n1w  = (const float*)d_in[9];
  const float* radW1= (const float*)d_in[10];
  const float* radb1= (const float*)d_in[11];
  const float* radW2= (const float*)d_in[12];
  const float* radb2= (const float*)d_in[13];
  const float* so2W = (const float*)d_in[14];
  const float* aW   = (const float*)d_in[15];
  const float* aV   = (const float*)d_in[16];
  const float* vW   = (const float*)d_in[17];
  const float* pW   = (const float*)d_in[18];
  const float* n2w  = (const float*)d_in[19];
  const float* fW1  = (const float*)d_in[20];
  const float* fb1  = (const float*)d_in[21];
  const float* fW2  = (const float*)d_in[22];
  const float* tg   = (const float*)d_in[23];
  const float* fg   = (const float*)d_in[24];
  const float* fnw  = (const float*)d_in[25];
  const float* enW1 = (const float*)d_in[26];
  const float* enb1 = (const float*)d_in[27];
  const float* enW2 = (const float*)d_in[28];
  const float* enb2 = (const float*)d_in[29];
  const int* nsp = (const int*)d_in[30];
  const int* snd = (const int*)d_in[31];
  const int* rcv = (const int*)d_in[32];
  int N = in_sizes[30];
  int E = in_sizes[31];
  float* out = (float*)d_out;

  float* ws = (float*)d_ws;
  size_t off = 0;
  unsigned short* rad0b = (unsigned short*)(ws + off); off += (size_t)E*192;  // E*384 bf16
  unsigned short* rad1b = (unsigned short*)(ws + off); off += (size_t)E*192;  // E*384 bf16
  float* logits = ws + off; off += (size_t)E*8;
  float* mx     = ws + off; off += (size_t)N*8;
  float* den    = ws + off; off += (size_t)N*8;
  float* x      = ws + off; off += (size_t)N*1600;
  float* xn     = ws + off; off += (size_t)N*1600;
  unsigned short* wsvb  = (unsigned short*)(ws + off); off += (size_t)6*16384/2;
  unsigned short* projb = (unsigned short*)(ws + off); off += (size_t)6*8192/2;
  int* cnt      = (int*)(ws + off); off += (size_t)N;
  int* rowptr   = (int*)(ws + off); off += (size_t)(N+1);
  int* fill     = (int*)(ws + off); off += (size_t)N;
  int* eixbuf   = (int*)(ws + off); off += (size_t)E;
  off = (off + 3) & ~((size_t)3);                       // 16B-align
  unsigned short* msgb  = (unsigned short*)(ws + off); off += (size_t)E*1216;  // [E][19][128] bf16
  unsigned short* tgp   = (unsigned short*)(ws + off); off += 9216;    // hi+lo 18432 shorts
  unsigned short* fgp   = (unsigned short*)(ws + off); off += 18432;   // hi+lo 36864 shorts
  unsigned short* wwp   = (unsigned short*)(ws + off); off += 32768;   // 2 layers x (w1 hi/lo + w2 hi/lo)
  unsigned short* enw1p = (unsigned short*)(ws + off); off += 8192;    // hi+lo 16384 shorts
  unsigned short* degw1p = (unsigned short*)(ws + off); off += 94208;   // 23*8*512 *2
  unsigned short* degw2p = (unsigned short*)(ws + off); off += 155648;  // 4*76*512 *2
  unsigned short* radw1p = (unsigned short*)(ws + off); off += 94208*2; // per layer
  unsigned short* radw2p = (unsigned short*)(ws + off); off += 49152*2; // per layer

  // CSR build (ordered chain) + ONE pack dispatch for all weight reformats
  zero_cnt_kernel<<<(N+255)/256, 256, 0, stream>>>(cnt, N);
  csr_count_kernel<<<(E+255)/256, 256, 0, stream>>>(rcv, cnt, E);
  csr_scan_kernel<<<1, 256, 0, stream>>>(cnt, rowptr, fill, N);
  csr_fill_kernel<<<(E+255)/256, 256, 0, stream>>>(rcv, fill, eixbuf, E);
  pack_all_kernel<<<210, 256, 0, stream>>>(so2W, vW, wsvb, pW, projb,
      tg, tgp, fg, fgp, fW1, fW2, wwp, enW1, enw1p,
      degW1, degw1p, degW2, degw2p, radW1, radw1p, radW2, radw2p);

  // ONE mlpf dispatch, 2x grid: deg+rad0 blocks + rad1-only blocks run concurrently
  int nb0 = (E+15)/16;
  mlpf_kernel<<<2*nb0, 256, 0, stream>>>(ev, ese, nsp,
      degw1p, degw1p+94208, degb1, degw2p, degw2p+155648, degb2,
      radw1p, radw1p+94208, radb1,
      radw2p, radw2p+49152, radb2,
      radw1p+188416, radw1p+188416+94208, radb1+128,
      radw2p+98304, radw2p+98304+49152, radb2+384,
      snd, rcv, eixbuf, msgb, rad0b, rad1b, nb0, E);
  node_sum_kernel<<<N, 256, 0, stream>>>(msgb, winv, rowptr, eixbuf, nsp, spe,
                                         n1w, x, xn, mx, den, 1, N);

  for (int i=0;i<2;i++){
    const unsigned short* radp = (i==0)? rad0b : rad1b;
    msg_kernel<<<(E+3)/4, 256, 0, stream>>>(xn, wig, radp,
                                            so2W + (size_t)i*24576,
                                            aW + (size_t)i*64*256, aV + (size_t)i*256,
                                            snd, rcv, eixbuf, msgb, logits, mx, E);
    den_kernel<<<(E*8+255)/256, 256, 0, stream>>>(logits, mx, rcv, den, E);
    attn_gemm_kernel<<<(E+15)/16, 256, 0, stream>>>(msgb,
                                                    wsvb + (size_t)i*3*16384, projb + (size_t)i*3*8192,
                                                    logits, mx, den, eixbuf, rcv, E);
    node_sum_kernel<<<N, 256, 0, stream>>>(msgb, winv, rowptr, eixbuf, nsp, spe,
                                           n2w + (size_t)i*320, x, xn, mx, den, 0, N);
    const float* nxt = (i==0) ? (n1w + 320) : fnw;
    grid_ffn_mfma_kernel<<<N, 256, 0, stream>>>(xn, tgp, fgp,
                                                wwp + (size_t)i*32768, wwp + (size_t)i*32768 + 16384,
                                                fb1 + (size_t)i*128, nxt, x, xn, N);
  }
  energy_mfma_kernel<<<N, 256, 0, stream>>>(xn, tgp, fg, enw1p, enb1, enW2, enb2, out, N);
}

// Round 22
// 2407.058 us; speedup vs baseline: 1.0985x; 1.0451x over previous
//
#include <hip/hip_runtime.h>
#include <hip/hip_bf16.h>
#include <math.h>

// EquiformerV2 block, fp32 activations. Round 28: attn_gemm wave-privatized —
// wave wv owns t-tiles {wv, wv+4, ...}, computing the FULL vv (8 nt) + oe (4 nt)
// for its tile into a private s_vv slice. The 38 block barriers per block
// (2 per t-tile, cross-wave vv->oe dependency) are deleted; only wave-local
// lgkmcnt ordering remains (node_sum r19 pattern). Same MFMA count/order ->
// bitwise-identical. pack_all 1-dispatch preamble + init_mxden fused (r27),
// mlpf grid-concat 2x (r25), rad bf16 (r17), rmsnorms fused (r22), msg+logits
// fused (r20), FFN/energy split-bf16 MFMA (r9). E=40000, N=2000, NL=2.

#define NRBF 600
#define DIN 728
#define GPTS 288
#define CH 8

typedef __attribute__((ext_vector_type(8))) short bf16x8;
typedef __attribute__((ext_vector_type(4))) float f32x4;

__constant__ int d_mg[19] = {0,1,0,1,2,1,0,1,2,2,1,0,1,2,2,1,0,1,2};
__constant__ int d_loc[25] = {0,1,1,1,2,2,2,2,2,3,3,3,3,3,3,3,4,4,4,4,4,4,4,4,4};
__constant__ int d_mg0[5]={0,2,6,11,16};
__constant__ int d_mg1[8]={1,3,5,7,10,12,15,17};
__constant__ int d_mg2[6]={4,8,9,13,14,18};

__device__ inline float silu_f(float v){ return v/(1.0f+__expf(-v)); }
__device__ inline float bf2f(unsigned short u){ return __uint_as_float(((unsigned)u)<<16); }
__device__ inline unsigned short f2bf(float f){
  unsigned b=__float_as_uint(f);
  return (unsigned short)((b + 0x7FFF + ((b>>16)&1)) >> 16);
}

__device__ inline void atomicMaxF(float* addr, float val){
  int* ia=(int*)addr;
  int old=*ia;
  while (__int_as_float(old) < val){
    int assumed=old;
    old = atomicCAS(ia, assumed, __float_as_int(val));
    if (old == assumed) break;
  }
}

// ---------------- CSR build ----------------
__global__ __launch_bounds__(256) void zero_cnt_kernel(int* cnt, int N){
  int i = blockIdx.x*256+threadIdx.x;
  if (i<N) cnt[i]=0;
}
__global__ __launch_bounds__(256) void csr_count_kernel(const int* __restrict__ rcv, int* cnt, int E){
  int i = blockIdx.x*256+threadIdx.x;
  if (i<E) atomicAdd(&cnt[rcv[i]],1);
}
__global__ __launch_bounds__(256) void csr_scan_kernel(const int* __restrict__ cnt,
    int* rowptr, int* fill, int N){
  __shared__ int s_part[256];
  int tid=threadIdx.x;
  int chunk=(N+255)/256;
  int lvals[12];
  int base=tid*chunk;
  int lsum=0;
  for (int i=0;i<chunk && i<12;i++){
    int v=(base+i<N)?cnt[base+i]:0;
    lvals[i]=lsum; lsum+=v;
  }
  s_part[tid]=lsum;
  __syncthreads();
  if (tid==0){
    int run=0;
    for (int t=0;t<256;t++){ int v=s_part[t]; s_part[t]=run; run+=v; }
  }
  __syncthreads();
  int off=s_part[tid];
  for (int i=0;i<chunk && i<12;i++){
    if (base+i<N){ rowptr[base+i]=off+lvals[i]; fill[base+i]=off+lvals[i]; }
  }
  if (tid==255) rowptr[N]=off+lsum;
}
__global__ __launch_bounds__(256) void csr_fill_kernel(const int* __restrict__ rcv,
    int* fill, int* eix, int E){
  int i = blockIdx.x*256+threadIdx.x;
  if (i<E){ int p=atomicAdd(&fill[rcv[i]],1); eix[p]=i; }
}

// ---------------- packB2g as device fn (hi/lo split, K zero-padded to 32) ----------------
__device__ inline void packB2g_dev(const float* __restrict__ src,
    unsigned short* __restrict__ dh, unsigned short* __restrict__ dl,
    int K, int Nn, int b, int b0, int nb){
  int ktiles=(K+31)>>5;
  int nnt=Nn>>4;
  int tot=ktiles*nnt*512;
  for (int idx=(b-b0)*256+threadIdx.x; idx<tot; idx+=nb*256){
    int f=idx>>9, r=idx&511, lane=r>>3, j=r&7;
    int kt=f/nnt, nt=f-kt*nnt;
    int k=kt*32+(lane>>4)*8+j, c=nt*16+(lane&15);
    float v=(k<K)? src[k*Nn+c] : 0.0f;
    unsigned short h=f2bf(v);
    dh[idx]=h;
    dl[idx]=f2bf(v-bf2f(h));
  }
}

// ---------------- ONE preamble pack dispatch, block-range routed (210 blocks) -------------
__global__ __launch_bounds__(256) void pack_all_kernel(
    const float* __restrict__ so2W, const float* __restrict__ valW, unsigned short* __restrict__ wsvb,
    const float* __restrict__ pW, unsigned short* __restrict__ projb,
    const float* __restrict__ tg, unsigned short* __restrict__ tgp,
    const float* __restrict__ fg, unsigned short* __restrict__ fgp,
    const float* __restrict__ fW1, const float* __restrict__ fW2, unsigned short* __restrict__ wwp,
    const float* __restrict__ enW1, unsigned short* __restrict__ enw1p,
    const float* __restrict__ degW1, unsigned short* __restrict__ degw1p,
    const float* __restrict__ degW2, unsigned short* __restrict__ degw2p,
    const float* __restrict__ radW1, unsigned short* __restrict__ radw1p,
    const float* __restrict__ radW2, unsigned short* __restrict__ radw2p){
  __shared__ float sB[8192];
  int b=blockIdx.x, tid=threadIdx.x;
  if (b<6){
    int i=b/3, g=b%3;
    const float* A = so2W + (size_t)i*24576 + g*8192;   // [128][64]
    const float* B = valW + (size_t)i*24576 + g*8192;   // [64][128]
    unsigned short* C = wsvb + (size_t)b*16384;
    for (int j=tid;j<2048;j+=256) ((float4*)sB)[j]=((const float4*)B)[j];
    __syncthreads();
    for (int idx=tid; idx<16384; idx+=256){
      int k=idx>>7, j=idx&127;
      float acc=0;
      #pragma unroll 4
      for (int o=0;o<64;o++) acc += A[k*64+o]*sB[o*128+j];
      int pos = ((k>>5)*8 + (j>>4))*512 + (((k>>3)&3)*16 + (j&15))*8 + (k&7);
      C[pos]=f2bf(acc);
    }
  } else if (b<12){
    int bb=b-6;
    const float* src = pW + (size_t)bb*8192;
    unsigned short* dst = projb + (size_t)bb*8192;
    for (int idx=tid; idx<8192; idx+=256){
      int k=idx>>6, j=idx&63;
      int pos = ((k>>5)*4 + (j>>4))*512 + (((k>>3)&3)*16 + (j&15))*8 + (k&7);
      dst[pos]=f2bf(src[idx]);
    }
  } else if (b==12){
    for (int idx=tid; idx<9216; idx+=256){
      int t=idx>>9, r=idx&511, lane=r>>3, j=r&7;
      int kl=(lane>>4)*8+j, row=t*16+(lane&15);
      float v=(kl<25)? tg[row*25+kl] : 0.0f;
      unsigned short h=f2bf(v);
      tgp[idx]=h;
      tgp[9216+idx]=f2bf(v-bf2f(h));
    }
  } else if (b==13){
    for (int idx=tid; idx<18432; idx+=256){
      int f=idx>>9, r=idx&511, lane=r>>3, j=r&7;
      int t=f>>1, mt=f&1;
      int row=mt*16+(lane&15), k=(lane>>4)*8+j;
      float v=(row<25 && k<16)? fg[row*288+t*16+k] : 0.0f;
      unsigned short h=f2bf(v);
      fgp[idx]=h;
      fgp[18432+idx]=f2bf(v-bf2f(h));
    }
  } else if (b<18){        // fW1 layer 0
    unsigned short* wl = wwp;
    packB2g_dev(fW1, wl, wl+8192, 64, 128, b, 14, 4);
  } else if (b<22){        // fW2 layer 0
    unsigned short* wl = wwp;
    packB2g_dev(fW2, wl+16384, wl+24576, 128, 64, b, 18, 4);
  } else if (b<26){        // fW1 layer 1
    unsigned short* wl = wwp + 32768;
    packB2g_dev(fW1+8192, wl, wl+8192, 64, 128, b, 22, 4);
  } else if (b<30){        // fW2 layer 1
    unsigned short* wl = wwp + 32768;
    packB2g_dev(fW2+8192, wl+16384, wl+24576, 128, 64, b, 26, 4);
  } else if (b<34){        // enW1
    packB2g_dev(enW1, enw1p, enw1p+8192, 64, 128, b, 30, 4);
  } else if (b<66){        // degW1
    packB2g_dev(degW1, degw1p, degw1p+94208, DIN, 128, b, 34, 32);
  } else if (b<114){       // degW2
    packB2g_dev(degW2, degw2p, degw2p+155648, 128, 1216, b, 66, 48);
  } else if (b<146){       // radW1 layer 0
    packB2g_dev(radW1, radw1p, radw1p+94208, DIN, 128, b, 114, 32);
  } else if (b<162){       // radW2 layer 0
    packB2g_dev(radW2, radw2p, radw2p+49152, 128, 384, b, 146, 16);
  } else if (b<194){       // radW1 layer 1
    unsigned short* r1 = radw1p + 188416;
    packB2g_dev(radW1+(size_t)DIN*128, r1, r1+94208, DIN, 128, b, 162, 32);
  } else {                 // radW2 layer 1 [194,210)
    unsigned short* r2 = radw2p + 98304;
    packB2g_dev(radW2+(size_t)128*384, r2, r2+49152, 128, 384, b, 194, 16);
  }
}

// ---------------- fused MLP, 2x grid: blocks [0,nb0) deg+rad0, [nb0,2nb0) rad1-only ------
__global__ __launch_bounds__(256) void mlpf_kernel(const float* __restrict__ ev,
    const float* __restrict__ ese, const int* __restrict__ nsp,
    const unsigned short* __restrict__ dw1h, const unsigned short* __restrict__ dw1l,
    const float* __restrict__ db1,
    const unsigned short* __restrict__ dw2h, const unsigned short* __restrict__ dw2l,
    const float* __restrict__ db2,
    const unsigned short* __restrict__ r1h0, const unsigned short* __restrict__ r1l0,
    const float* __restrict__ rb10,
    const unsigned short* __restrict__ r2h0, const unsigned short* __restrict__ r2l0,
    const float* __restrict__ rb20,
    const unsigned short* __restrict__ r1h1, const unsigned short* __restrict__ r1l1,
    const float* __restrict__ rb11,
    const unsigned short* __restrict__ r2h1, const unsigned short* __restrict__ r2l1,
    const float* __restrict__ rb21,
    const int* __restrict__ snd, const int* __restrict__ rcv, const int* __restrict__ eix,
    unsigned short* __restrict__ degout,
    unsigned short* __restrict__ rad0out, unsigned short* __restrict__ rad1out,
    int nb0, int E){
  int tid=threadIdx.x, wv=tid>>6, lane=tid&63;
  int lanelo=lane&15, khi=lane>>4;
  int do_deg = (blockIdx.x < (unsigned)nb0) ? 1 : 0;
  int bb = do_deg ? blockIdx.x : (blockIdx.x - nb0);
  int p0=bb*16;
  const unsigned short* r1h = do_deg? r1h0 : r1h1;
  const unsigned short* r1l = do_deg? r1l0 : r1l1;
  const float* rb1 = do_deg? rb10 : rb11;
  const unsigned short* r2h = do_deg? r2h0 : r2h1;
  const unsigned short* r2l = do_deg? r2l0 : r2l1;
  const float* rb2 = do_deg? rb20 : rb21;
  unsigned short* radout = do_deg? rad0out : rad1out;
  __shared__ unsigned short s_eeh[4096], s_eel[4096];   // CH ktiles
  __shared__ unsigned short s_h1h[2048], s_h1l[2048];   // [16][128] swizzled
  __shared__ float s_d[16]; __shared__ int s_ss[16], s_rs[16], s_e[16];
  if (tid<16){
    int p=p0+tid;
    int e=(p<E)? eix[p] : -1;
    s_e[tid]=e;
    if (e>=0){
      float vx=ev[3*e], vy=ev[3*e+1], vz=ev[3*e+2];
      s_d[tid]=sqrtf(vx*vx+vy*vy+vz*vz+1e-12f);
      s_ss[tid]=nsp[snd[e]]; s_rs[tid]=nsp[rcv[e]];
    } else { s_d[tid]=0.0f; s_ss[tid]=0; s_rs[tid]=0; }
  }
  __syncthreads();
  const float step=5.0f/599.0f, inv_std=1.0f/(2.0f*step);
  int nta=wv*2, ntb=nta+1;
  f32x4 z4={0,0,0,0};
  f32x4 aD0=z4,aD1=z4,aR0=z4,aR1=z4;
  for (int c=0;c<23;c+=CH){
    int ncur=23-c; if (ncur>CH) ncur=CH;
    for (int idx=tid; idx<ncur*512; idx+=256){
      int f=idx>>9, r=idx&511, ln=r>>3, j=r&7;
      int k=(c+f)*32+((ln>>4)<<3)+j, row=ln&15;
      float v=0.0f;
      if (k<NRBF){ float t=(s_d[row]-k*step)*inv_std; v=__expf(-0.5f*t*t); }
      else if (k<NRBF+64) v=ese[s_ss[row]*128+(k-NRBF)];
      else if (k<DIN)     v=ese[s_rs[row]*128+64+(k-NRBF-64)];
      unsigned short h=f2bf(v);
      s_eeh[idx]=h; s_eel[idx]=f2bf(v-bf2f(h));
    }
    __syncthreads();
    for (int f=0; f<ncur; f++){
      int kt=c+f;
      bf16x8 Ah=*(const bf16x8*)(s_eeh + f*512 + lane*8);
      bf16x8 Al=*(const bf16x8*)(s_eel + f*512 + lane*8);
      size_t ba=(size_t)(kt*8+nta)*512+lane*8;
      {
        bf16x8 Bh=*(const bf16x8*)(r1h+ba), Bl=*(const bf16x8*)(r1l+ba);
        bf16x8 Bh2=*(const bf16x8*)(r1h+ba+512), Bl2=*(const bf16x8*)(r1l+ba+512);
        aR0=__builtin_amdgcn_mfma_f32_16x16x32_bf16(Ah,Bh,aR0,0,0,0);
        aR0=__builtin_amdgcn_mfma_f32_16x16x32_bf16(Al,Bh,aR0,0,0,0);
        aR0=__builtin_amdgcn_mfma_f32_16x16x32_bf16(Ah,Bl,aR0,0,0,0);
        aR1=__builtin_amdgcn_mfma_f32_16x16x32_bf16(Ah,Bh2,aR1,0,0,0);
        aR1=__builtin_amdgcn_mfma_f32_16x16x32_bf16(Al,Bh2,aR1,0,0,0);
        aR1=__builtin_amdgcn_mfma_f32_16x16x32_bf16(Ah,Bl2,aR1,0,0,0);
      }
      if (do_deg){
        bf16x8 Bh=*(const bf16x8*)(dw1h+ba), Bl=*(const bf16x8*)(dw1l+ba);
        bf16x8 Bh2=*(const bf16x8*)(dw1h+ba+512), Bl2=*(const bf16x8*)(dw1l+ba+512);
        aD0=__builtin_amdgcn_mfma_f32_16x16x32_bf16(Ah,Bh,aD0,0,0,0);
        aD0=__builtin_amdgcn_mfma_f32_16x16x32_bf16(Al,Bh,aD0,0,0,0);
        aD0=__builtin_amdgcn_mfma_f32_16x16x32_bf16(Ah,Bl,aD0,0,0,0);
        aD1=__builtin_amdgcn_mfma_f32_16x16x32_bf16(Ah,Bh2,aD1,0,0,0);
        aD1=__builtin_amdgcn_mfma_f32_16x16x32_bf16(Al,Bh2,aD1,0,0,0);
        aD1=__builtin_amdgcn_mfma_f32_16x16x32_bf16(Ah,Bl2,aD1,0,0,0);
      }
    }
    __syncthreads();
  }
  int nmlp = do_deg ? 2 : 1;
  #pragma unroll 1
  for (int it=0; it<nmlp; it++){
    int is_deg = (it==1);
    f32x4 a0 = is_deg ? aD0 : aR0;
    f32x4 a1 = is_deg ? aD1 : aR1;
    const float* b1 = is_deg ? db1 : rb1;
    #pragma unroll
    for (int q=0;q<4;q++){
      int row=khi*4+q;
      {
        int col=nta*16+lanelo;
        float v=silu_f(a0[q]+b1[col]);
        int pos=row*128 + (((col>>3)^(row&7))<<3) + (col&7);
        unsigned short h=f2bf(v);
        s_h1h[pos]=h; s_h1l[pos]=f2bf(v-bf2f(h));
      }
      {
        int col=ntb*16+lanelo;
        float v=silu_f(a1[q]+b1[col]);
        int pos=row*128 + (((col>>3)^(row&7))<<3) + (col&7);
        unsigned short h=f2bf(v);
        s_h1h[pos]=h; s_h1l[pos]=f2bf(v-bf2f(h));
      }
    }
    __syncthreads();
    bf16x8 Ahh[4],Ahl[4];
    #pragma unroll
    for (int kt=0;kt<4;kt++){
      int o=lanelo*128 + (((kt*4+khi)^(lanelo&7))<<3);
      Ahh[kt]=*(const bf16x8*)(s_h1h+o);
      Ahl[kt]=*(const bf16x8*)(s_h1l+o);
    }
    __syncthreads();
    if (is_deg){
      for (int nt=wv; nt<76; nt+=4){
        f32x4 acc=z4;
        #pragma unroll
        for (int kt=0;kt<4;kt++){
          size_t bo=(size_t)(kt*76+nt)*512+lane*8;
          bf16x8 Bh=*(const bf16x8*)(dw2h+bo), Bl=*(const bf16x8*)(dw2l+bo);
          acc=__builtin_amdgcn_mfma_f32_16x16x32_bf16(Ahh[kt],Bh,acc,0,0,0);
          acc=__builtin_amdgcn_mfma_f32_16x16x32_bf16(Ahl[kt],Bh,acc,0,0,0);
          acc=__builtin_amdgcn_mfma_f32_16x16x32_bf16(Ahh[kt],Bl,acc,0,0,0);
        }
        int col=nt*16+lanelo;
        float bb2=db2[col];
        #pragma unroll
        for (int q=0;q<4;q++){
          int p=p0+khi*4+q;
          if (p<E) degout[(size_t)p*1216+col]=f2bf(acc[q]+bb2);
        }
      }
    } else {
      for (int nt=wv; nt<24; nt+=4){
        f32x4 acc=z4;
        #pragma unroll
        for (int kt=0;kt<4;kt++){
          size_t bo=(size_t)(kt*24+nt)*512+lane*8;
          bf16x8 Bh=*(const bf16x8*)(r2h+bo), Bl=*(const bf16x8*)(r2l+bo);
          acc=__builtin_amdgcn_mfma_f32_16x16x32_bf16(Ahh[kt],Bh,acc,0,0,0);
          acc=__builtin_amdgcn_mfma_f32_16x16x32_bf16(Ahl[kt],Bh,acc,0,0,0);
          acc=__builtin_amdgcn_mfma_f32_16x16x32_bf16(Ahh[kt],Bl,acc,0,0,0);
        }
        int col=nt*16+lanelo;
        float bb2=rb2[col];
        #pragma unroll
        for (int q=0;q<4;q++){
          int e=s_e[khi*4+q];
          if (e>=0) radout[(size_t)e*384+col]=f2bf(acc[q]+bb2);
        }
      }
    }
  }
}

// ---------------- wave-per-edge node gather + prefetch + fused rms-norm + mx/den init -----
__global__ __launch_bounds__(256) void node_sum_kernel(const unsigned short* __restrict__ msgb,
    const float* __restrict__ winv, const int* __restrict__ rowptr, const int* __restrict__ eix,
    const int* __restrict__ nsp, const float* __restrict__ spe,
    const float* __restrict__ nw, float* __restrict__ x, float* __restrict__ xn,
    float* __restrict__ mx, float* __restrict__ den,
    int mode, int N){
  int n=blockIdx.x, tid=threadIdx.x, wv=tid>>6, lane=tid&63;
  __shared__ float s_winv[4][480];
  __shared__ unsigned short s_oe[4][1216];
  __shared__ float4 s_red[4][400];
  __shared__ float4 s_ms4[16];
  if (tid<8){ mx[n*8+tid]=-3.0e38f; den[n*8+tid]=0.0f; }   // init for the NEXT msg pass
  int row0=rowptr[n];
  int cnt=rowptr[n+1]-row0;
  float4 acc[7];
  #pragma unroll
  for (int t=0;t<7;t++) acc[t]=make_float4(0,0,0,0);
  float wpre[8];
  int4 opre[3];
  int j=wv;
  if (j<cnt){
    int p=row0+j;
    int e=eix[p];
    #pragma unroll
    for (int t=0;t<8;t++){ int k=lane+t*64; wpre[t]=(k<475)? winv[(size_t)e*475+k] : 0.0f; }
    if (mode==1){
      #pragma unroll
      for (int t=0;t<3;t++){
        int k=lane+t*64;
        opre[t]=(k<152)? *(const int4*)(msgb+(size_t)p*1216+(size_t)k*8) : make_int4(0,0,0,0);
      }
    } else {
      #pragma unroll
      for (int t=0;t<3;t++){
        int k=lane+t*64;
        if (k<152){ int m=k>>3, jj=k&7; opre[t]=*(const int4*)(msgb+(size_t)p*2432+m*128+jj*8); }
        else opre[t]=make_int4(0,0,0,0);
      }
    }
  }
  for (; j<cnt; j+=4){
    asm volatile("s_waitcnt lgkmcnt(0)" ::: "memory");
    #pragma unroll
    for (int t=0;t<8;t++){ int k=lane+t*64; if (k<475) s_winv[wv][k]=wpre[t]; }
    #pragma unroll
    for (int t=0;t<3;t++){ int k=lane+t*64; if (k<152) ((int4*)s_oe[wv])[k]=opre[t]; }
    int jn=j+4;
    if (jn<cnt){
      int p=row0+jn;
      int e=eix[p];
      #pragma unroll
      for (int t=0;t<8;t++){ int k=lane+t*64; wpre[t]=(k<475)? winv[(size_t)e*475+k] : 0.0f; }
      if (mode==1){
        #pragma unroll
        for (int t=0;t<3;t++){
          int k=lane+t*64;
          opre[t]=(k<152)? *(const int4*)(msgb+(size_t)p*1216+(size_t)k*8) : make_int4(0,0,0,0);
        }
      } else {
        #pragma unroll
        for (int t=0;t<3;t++){
          int k=lane+t*64;
          if (k<152){ int m=k>>3, jj=k&7; opre[t]=*(const int4*)(msgb+(size_t)p*2432+m*128+jj*8); }
          else opre[t]=make_int4(0,0,0,0);
        }
      }
    }
    asm volatile("s_waitcnt lgkmcnt(0)" ::: "memory");
    const unsigned* o2=(const unsigned*)s_oe[wv];
    #pragma unroll
    for (int t=0;t<7;t++){
      int sI=lane+t*64;
      if (sI<400){
        int l=sI>>4, c4=sI&15;
        const float* wr=s_winv[wv]+l*19;
        float4 a=acc[t];
        #pragma unroll
        for (int m=0;m<19;m++){
          float w=wr[m];
          unsigned ua=o2[m*32+c4*2], ub=o2[m*32+c4*2+1];
          a.x+=w*bf2f((unsigned short)(ua&0xffffu));
          a.y+=w*bf2f((unsigned short)(ua>>16));
          a.z+=w*bf2f((unsigned short)(ub&0xffffu));
          a.w+=w*bf2f((unsigned short)(ub>>16));
        }
        acc[t]=a;
      }
    }
  }
  asm volatile("s_waitcnt lgkmcnt(0)" ::: "memory");
  #pragma unroll
  for (int t=0;t<7;t++){
    int sI=lane+t*64;
    if (sI<400) s_red[wv][sI]=acc[t];
  }
  __syncthreads();
  float4* xp=(float4*)(x+(size_t)n*1600);
  int j0=tid, j1=tid+256;
  bool h1=(j1<400);
  float4 v0, v1=make_float4(0,0,0,0);
  if (mode==0){
    {
      float4 a=s_red[0][j0], b=s_red[1][j0], c=s_red[2][j0], d=s_red[3][j0];
      float4 cur=xp[j0];
      cur.x+=a.x+b.x+c.x+d.x;
      cur.y+=a.y+b.y+c.y+d.y;
      cur.z+=a.z+b.z+c.z+d.z;
      cur.w+=a.w+b.w+c.w+d.w;
      v0=cur; xp[j0]=cur;
    }
    if (h1){
      float4 a=s_red[0][j1], b=s_red[1][j1], c=s_red[2][j1], d=s_red[3][j1];
      float4 cur=xp[j1];
      cur.x+=a.x+b.x+c.x+d.x;
      cur.y+=a.y+b.y+c.y+d.y;
      cur.z+=a.z+b.z+c.z+d.z;
      cur.w+=a.w+b.w+c.w+d.w;
      v1=cur; xp[j1]=cur;
    }
  } else {
    int sp=nsp[n];
    const float4* sp4=(const float4*)(spe+(size_t)sp*64);
    {
      int l=j0>>4, c4=j0&15;
      float4 a=s_red[0][j0], b=s_red[1][j0], c=s_red[2][j0], d=s_red[3][j0];
      float4 base=(l==0)? sp4[c4] : make_float4(0,0,0,0);
      float4 o;
      o.x=base.x+0.05f*(a.x+b.x+c.x+d.x);
      o.y=base.y+0.05f*(a.y+b.y+c.y+d.y);
      o.z=base.z+0.05f*(a.z+b.z+c.z+d.z);
      o.w=base.w+0.05f*(a.w+b.w+c.w+d.w);
      v0=o; xp[j0]=o;
    }
    if (h1){
      float4 a=s_red[0][j1], b=s_red[1][j1], c=s_red[2][j1], d=s_red[3][j1];
      float4 o;
      o.x=0.05f*(a.x+b.x+c.x+d.x);
      o.y=0.05f*(a.y+b.y+c.y+d.y);
      o.z=0.05f*(a.z+b.z+c.z+d.z);
      o.w=0.05f*(a.w+b.w+c.w+d.w);
      v1=o; xp[j1]=o;
    }
  }
  __syncthreads();   // all s_red reads done -> safe to alias as partial buffer
  float4* s_p4=(float4*)s_red;
  float4 a4;
  a4.x=v0.x*v0.x; a4.y=v0.y*v0.y; a4.z=v0.z*v0.z; a4.w=v0.w*v0.w;
  if (h1){ a4.x+=v1.x*v1.x; a4.y+=v1.y*v1.y; a4.z+=v1.z*v1.z; a4.w+=v1.w*v1.w; }
  s_p4[tid]=a4;
  __syncthreads();
  if (tid<16){
    float4 s=make_float4(0,0,0,0);
    #pragma unroll
    for (int k=0;k<16;k++){
      float4 p=s_p4[tid+16*k];
      s.x+=p.x; s.y+=p.y; s.z+=p.z; s.w+=p.w;
    }
    float4 m;
    m.x=rsqrtf(s.x*(1.0f/25.0f)+1e-6f);
    m.y=rsqrtf(s.y*(1.0f/25.0f)+1e-6f);
    m.z=rsqrtf(s.z*(1.0f/25.0f)+1e-6f);
    m.w=rsqrtf(s.w*(1.0f/25.0f)+1e-6f);
    s_ms4[tid]=m;
  }
  __syncthreads();
  float4* xnp=(float4*)(xn+(size_t)n*1600);
  {
    int l=j0>>4, g=j0&15;
    float4 m=s_ms4[g];
    const float* wr=nw + d_loc[l]*64 + g*4;
    float4 o;
    o.x=v0.x*m.x*wr[0]; o.y=v0.y*m.y*wr[1]; o.z=v0.z*m.z*wr[2]; o.w=v0.w*m.w*wr[3];
    xnp[j0]=o;
  }
  if (h1){
    int l=j1>>4, g=j1&15;
    float4 m=s_ms4[g];
    const float* wr=nw + d_loc[l]*64 + g*4;
    float4 o;
    o.x=v1.x*m.x*wr[0]; o.y=v1.y*m.y*wr[1]; o.z=v1.z*m.z*wr[2]; o.w=v1.w*m.w*wr[3];
    xnp[j1]=o;
  }
}

__global__ __launch_bounds__(256) void den_kernel(const float* __restrict__ logits,
    const float* __restrict__ mx, const int* __restrict__ rcv,
    float* __restrict__ den, int E){
  int idx = blockIdx.x*256+threadIdx.x;
  if (idx >= E*8) return;
  int e = idx>>3, hd = idx&7, r = rcv[e];
  atomicAdd(&den[r*8+hd], __expf(logits[idx]-mx[r*8+hd]));
}

// ---------------- pass 2a: msg + fused alpha-logits, wave-per-edge (4 edges/block) -----------
__global__ __launch_bounds__(256) void msg_kernel(const float* __restrict__ xn,
    const float* __restrict__ wig, const unsigned short* __restrict__ radb,
    const float* __restrict__ so2W, const float* __restrict__ alphaW, const float* __restrict__ alphaV,
    const int* __restrict__ snd, const int* __restrict__ rcv, const int* __restrict__ eix,
    unsigned short* __restrict__ msgb, float* __restrict__ logits, float* __restrict__ mx, int E){
  __shared__ float s_wig[1900];   // 4 waves x 475
  __shared__ float s_m0[4][128];
  __shared__ float s_sh0[4][64];
  int tid=threadIdx.x, wv=tid>>6, lane=tid&63;
  int p=blockIdx.x*4+wv;
  bool act=(p<E);
  int pc=act? p : (E-1);
  int e=eix[pc];
  int node=(lane<32)? snd[e] : rcv[e];
  int c2=(lane&31)*2;
  int col0=c2+((lane>>5)<<6);   // global col, even
  const float* xb=xn+(size_t)node*1600+c2;
  float ca[25], cb[25];
  #pragma unroll
  for (int l=0;l<25;l++){
    float2 v=*(const float2*)(xb+l*64);
    ca[l]=v.x; cb[l]=v.y;
  }
  float* swig=s_wig+wv*475;
  for (int j=lane;j<475;j+=64) swig[j]=wig[(size_t)e*475+j];
  float ra0,ra1,rb0,rb1,rc0,rc1;
  {
    const unsigned short* rb_=radb+(size_t)e*384;
    unsigned u0=*(const unsigned*)(rb_+col0);
    unsigned u1=*(const unsigned*)(rb_+128+col0);
    unsigned u2=*(const unsigned*)(rb_+256+col0);
    ra0=bf2f((unsigned short)(u0&0xffffu)); ra1=bf2f((unsigned short)(u0>>16));
    rb0=bf2f((unsigned short)(u1&0xffffu)); rb1=bf2f((unsigned short)(u1>>16));
    rc0=bf2f((unsigned short)(u2&0xffffu)); rc1=bf2f((unsigned short)(u2>>16));
  }
  __syncthreads();
  unsigned short* dst=msgb+(size_t)pc*2432+col0;
  constexpr int mgc[19]={0,1,0,1,2,1,0,1,2,2,1,0,1,2,2,1,0,1,2};
  float m0a=0.0f, m0b=0.0f;
  if (act){
    #pragma unroll
    for (int m=0;m<19;m++){
      float a0=0.0f,a1=0.0f;
      const float* wr=swig+m*25;
      #pragma unroll
      for (int l=0;l<25;l++){ float w=wr[l]; a0+=w*ca[l]; a1+=w*cb[l]; }
      float r0,r1;
      if (mgc[m]==0){ r0=ra0; r1=ra1; }
      else if (mgc[m]==1){ r0=rb0; r1=rb1; }
      else { r0=rc0; r1=rc1; }
      a0*=r0; a1*=r1;
      if (m==0){ m0a=a0; m0b=a1; }
      unsigned packv=((unsigned)f2bf(a1)<<16)|(unsigned)f2bf(a0);
      *(unsigned*)(dst+m*128)=packv;
    }
  }
  // ---- fused alpha-logits chain (wave-local; inactive waves compute garbage, writes guarded)
  s_m0[wv][col0]=m0a; s_m0[wv][col0+1]=m0b;
  asm volatile("s_waitcnt lgkmcnt(0)" ::: "memory");
  {
    const float* m0p=s_m0[wv];
    float accs=0.0f;
    #pragma unroll 8
    for (int k=0;k<128;k++) accs += m0p[k]*so2W[k*64+lane];
    s_sh0[wv][lane]=silu_f(accs);
  }
  asm volatile("s_waitcnt lgkmcnt(0)" ::: "memory");
  {
    const float* sh=s_sh0[wv];
    int j0=lane*4;
    float4 av=*(const float4*)(alphaV+j0);
    float4 aacc={0,0,0,0};
    #pragma unroll 8
    for (int o=0;o<64;o++){
      float s=sh[o];
      float4 w=*(const float4*)(alphaW+o*256+j0);
      aacc.x+=s*w.x; aacc.y+=s*w.y; aacc.z+=s*w.z; aacc.w+=s*w.w;
    }
    float part = silu_f(aacc.x)*av.x + silu_f(aacc.y)*av.y
               + silu_f(aacc.z)*av.z + silu_f(aacc.w)*av.w;
    part += __shfl_xor(part,1);
    part += __shfl_xor(part,2);
    part += __shfl_xor(part,4);
    if (act && (lane&7)==0){
      int h=lane>>3;
      int r=rcv[e];
      logits[(size_t)e*8+h]=part;
      atomicMaxF(&mx[r*8+h], part);
    }
  }
}

// ---------------- pass 2b: 16-edge MFMA GEMM, wave-per-t-tile (ZERO block barriers in loop) --
// Wave wv owns t in {wv, wv+4, ...}: computes full vv (8 nt) into private s_vv[wv],
// then oe (4 nt) from it. Same per-output kt-order as before -> bitwise identical.
__global__ __launch_bounds__(256) void attn_gemm_kernel(unsigned short* __restrict__ msgb,
    const unsigned short* __restrict__ wsvp, const unsigned short* __restrict__ projp,
    const float* __restrict__ logits, const float* __restrict__ mx, const float* __restrict__ den,
    const int* __restrict__ eix, const int* __restrict__ rcv, int E){
  int tid=threadIdx.x, wv=tid>>6, lane=tid&63;
  int lanelo=lane&15, khi=lane>>4;
  int p0=blockIdx.x*16;
  __shared__ unsigned short s_vv[4][2176];   // per-wave [16][136]
  __shared__ float s_attn[16][8];
  __shared__ short s_r2e[304], s_r2m[304];
  for (int j=tid;j<304;j+=256){
    int e,m;
    if (j<80){ e=j/5; m=d_mg0[j%5]; }
    else if (j<208){ int q=j-80; e=q>>3; m=d_mg1[q&7]; }
    else { int q=j-208; e=q/6; m=d_mg2[q%6]; }
    s_r2e[j]=(short)e; s_r2m[j]=(short)m;
  }
  if (tid<128){
    int i=tid>>3, h=tid&7, p=p0+i;
    float a=0.0f;
    if (p<E){
      int e=eix[p]; int r=rcv[e];
      a=__expf(logits[(size_t)e*8+h]-mx[r*8+h])/(den[r*8+h]+1e-12f);
    }
    s_attn[i][h]=a;
  }
  __syncthreads();
  const int4* wp4=(const int4*)wsvp;
  const int4* pp4=(const int4*)projp;
  unsigned short* svv = s_vv[wv];
  for (int t=wv; t<19; t+=4){
    int g=(t<5)?0:((t<13)?1:2);
    int R=t*16+lanelo;
    int ei=s_r2e[R], mi=s_r2m[R];
    int pp=p0+ei;
    size_t abase=((size_t)((pp<E)?pp:0))*2432 + (size_t)mi*128;
    bf16x8 A[4];
    #pragma unroll
    for (int kt=0;kt<4;kt++)
      A[kt]=*(const bf16x8*)(msgb + abase + kt*32 + khi*8);
    // WAR: previous t's A2 reads from svv must retire before overwriting
    asm volatile("s_waitcnt lgkmcnt(0)" ::: "memory");
    #pragma unroll
    for (int nt=0;nt<8;nt++){
      f32x4 acc={0,0,0,0};
      #pragma unroll
      for (int kt=0;kt<4;kt++){
        int4 tt=wp4[g*2048+(kt*8+nt)*64+lane];
        acc=__builtin_amdgcn_mfma_f32_16x16x32_bf16(A[kt],*(bf16x8*)&tt,acc,0,0,0);
      }
      int col=nt*16+lanelo;
      #pragma unroll
      for (int q=0;q<4;q++){
        int r16=khi*4+q;
        int ei2=s_r2e[t*16+r16];
        svv[r16*136+col]=f2bf(acc[q]*s_attn[ei2][nt]);
      }
    }
    // RAW: vv writes must land before A2 reads (wave-local)
    asm volatile("s_waitcnt lgkmcnt(0)" ::: "memory");
    bf16x8 A2[4];
    #pragma unroll
    for (int kt=0;kt<4;kt++)
      A2[kt]=*(const bf16x8*)(svv + lanelo*136 + kt*32 + khi*8);
    #pragma unroll
    for (int nt=0;nt<4;nt++){
      f32x4 acc={0,0,0,0};
      #pragma unroll
      for (int kt=0;kt<4;kt++){
        int4 tt=pp4[g*1024+(kt*4+nt)*64+lane];
        acc=__builtin_amdgcn_mfma_f32_16x16x32_bf16(A2[kt],*(bf16x8*)&tt,acc,0,0,0);
      }
      int col=nt*16+lanelo;
      #pragma unroll
      for (int q=0;q<4;q++){
        int R2=t*16+khi*4+q;
        int pi=p0+s_r2e[R2];
        if (pi<E) msgb[(size_t)pi*2432 + (size_t)s_r2m[R2]*128 + col]=f2bf(acc[q]);
      }
    }
  }
}

// ---------------- S2 grid FFN via split-bf16 MFMA + FUSED next-layer rms-norm -------------
__global__ __launch_bounds__(256) void grid_ffn_mfma_kernel(const float* __restrict__ xnin,
    const unsigned short* __restrict__ tgp, const unsigned short* __restrict__ fgp,
    const unsigned short* __restrict__ w1p, const unsigned short* __restrict__ w2p,
    const float* __restrict__ b1, const float* __restrict__ nw,
    float* __restrict__ x, float* __restrict__ xnout, int N){
  int n=blockIdx.x, tid=threadIdx.x, wv=tid>>6, lane=tid&63;
  int lanelo=lane&15, khi=lane>>4;
  __shared__ __align__(16) char s_mem[74240];
  unsigned short* s_w1=(unsigned short*)s_mem;             // hi 8192 | lo 8192 shorts (32KB)
  unsigned short* s_xn=(unsigned short*)(s_mem+32768);     // hi 2048 | lo 2048 shorts (8KB)
  float* s_b1=(float*)(s_mem+40960);                       // 128 f
  unsigned short* scr=(unsigned short*)(s_mem+41472)+(size_t)wv*4096;  // 8KB/wave
  for (int j=tid;j<2048;j+=256) ((int4*)s_w1)[j]=((const int4*)w1p)[j];
  if (tid<128) s_b1[tid]=b1[tid];
  { int4 z={0,0,0,0}; for (int j=tid;j<512;j+=256) ((int4*)s_xn)[j]=z; }
  __syncthreads();
  {
    const float* xr=xnin+(size_t)n*1600;
    for (int j=tid;j<1600;j+=256){
      int k=j>>6, c=j&63;
      float v=xr[j];
      unsigned short h=f2bf(v);
      s_xn[c*32+k]=h;
      s_xn[2048+c*32+k]=f2bf(v-bf2f(h));
    }
  }
  __syncthreads();
  bf16x8 XBh[4],XBl[4];
  #pragma unroll
  for (int ct=0;ct<4;ct++){
    int o=(ct*16+lanelo)*32 + khi*8;
    XBh[ct]=*(const bf16x8*)(s_xn+o);
    XBl[ct]=*(const bf16x8*)(s_xn+2048+o);
  }
  f32x4 oacc[2][4];
  #pragma unroll
  for (int mt=0;mt<2;mt++)
    #pragma unroll
    for (int nt=0;nt<4;nt++){ f32x4 z={0,0,0,0}; oacc[mt][nt]=z; }
  for (int t=wv;t<18;t+=4){
    bf16x8 Atgh=*(const bf16x8*)(tgp + t*512 + lane*8);
    bf16x8 Atgl=*(const bf16x8*)(tgp + 9216 + t*512 + lane*8);
    #pragma unroll
    for (int ct=0;ct<4;ct++){
      f32x4 g={0,0,0,0};
      g=__builtin_amdgcn_mfma_f32_16x16x32_bf16(Atgh,XBh[ct],g,0,0,0);
      g=__builtin_amdgcn_mfma_f32_16x16x32_bf16(Atgl,XBh[ct],g,0,0,0);
      g=__builtin_amdgcn_mfma_f32_16x16x32_bf16(Atgh,XBl[ct],g,0,0,0);
      #pragma unroll
      for (int q=0;q<4;q++){
        int row=khi*4+q, col=ct*16+lanelo;
        int pos=row*64 + (((col>>3)^(row&7))<<3) + (col&7);
        float v=g[q]; unsigned short h=f2bf(v);
        scr[pos]=h; scr[1024+pos]=f2bf(v-bf2f(h));
      }
    }
    bf16x8 Agh[2],Agl[2];
    #pragma unroll
    for (int kt=0;kt<2;kt++){
      int o=lanelo*64 + (((kt*4+khi)^(lanelo&7))<<3);
      Agh[kt]=*(const bf16x8*)(scr+o);
      Agl[kt]=*(const bf16x8*)(scr+1024+o);
    }
    #pragma unroll
    for (int nt=0;nt<8;nt++){
      f32x4 h={0,0,0,0};
      #pragma unroll
      for (int kt=0;kt<2;kt++){
        bf16x8 Bh=*(const bf16x8*)(s_w1 + (kt*8+nt)*512 + lane*8);
        bf16x8 Bl=*(const bf16x8*)(s_w1 + 8192 + (kt*8+nt)*512 + lane*8);
        h=__builtin_amdgcn_mfma_f32_16x16x32_bf16(Agh[kt],Bh,h,0,0,0);
        h=__builtin_amdgcn_mfma_f32_16x16x32_bf16(Agl[kt],Bh,h,0,0,0);
        h=__builtin_amdgcn_mfma_f32_16x16x32_bf16(Agh[kt],Bl,h,0,0,0);
      }
      #pragma unroll
      for (int q=0;q<4;q++){
        int row=khi*4+q, col=nt*16+lanelo;
        float v=silu_f(h[q]+s_b1[col]);
        int pos=row*128 + (((col>>3)^(row&7))<<3) + (col&7);
        unsigned short hh=f2bf(v);
        scr[pos]=hh; scr[2048+pos]=f2bf(v-bf2f(hh));
      }
    }
    bf16x8 Ahh[4],Ahl[4];
    #pragma unroll
    for (int kt=0;kt<4;kt++){
      int o=lanelo*128 + (((kt*4+khi)^(lanelo&7))<<3);
      Ahh[kt]=*(const bf16x8*)(scr+o);
      Ahl[kt]=*(const bf16x8*)(scr+2048+o);
    }
    #pragma unroll
    for (int nt=0;nt<4;nt++){
      f32x4 o4={0,0,0,0};
      #pragma unroll
      for (int kt=0;kt<4;kt++){
        bf16x8 Bh=*(const bf16x8*)(w2p + (kt*4+nt)*512 + lane*8);
        bf16x8 Bl=*(const bf16x8*)(w2p + 8192 + (kt*4+nt)*512 + lane*8);
        o4=__builtin_amdgcn_mfma_f32_16x16x32_bf16(Ahh[kt],Bh,o4,0,0,0);
        o4=__builtin_amdgcn_mfma_f32_16x16x32_bf16(Ahl[kt],Bh,o4,0,0,0);
        o4=__builtin_amdgcn_mfma_f32_16x16x32_bf16(Ahh[kt],Bl,o4,0,0,0);
      }
      #pragma unroll
      for (int q=0;q<4;q++){
        int ch=nt*16+lanelo, rowk=khi*4+q;
        int pos=ch*32 + (((rowk>>3)^(ch&3))<<3) + (rowk&7);
        float v=o4[q]; unsigned short hh=f2bf(v);
        scr[pos]=hh; scr[2048+pos]=f2bf(v-bf2f(hh));
      }
    }
    bf16x8 Boh[4],Bol[4];
    #pragma unroll
    for (int nt=0;nt<4;nt++){
      int ch=nt*16+lanelo;
      int o=ch*32 + ((khi^(ch&3))<<3);
      Boh[nt]=*(const bf16x8*)(scr+o);
      Bol[nt]=*(const bf16x8*)(scr+2048+o);
    }
    #pragma unroll
    for (int mt=0;mt<2;mt++){
      bf16x8 Afh=*(const bf16x8*)(fgp + (t*2+mt)*512 + lane*8);
      bf16x8 Afl=*(const bf16x8*)(fgp + 18432 + (t*2+mt)*512 + lane*8);
      #pragma unroll
      for (int nt=0;nt<4;nt++){
        oacc[mt][nt]=__builtin_amdgcn_mfma_f32_16x16x32_bf16(Afh,Boh[nt],oacc[mt][nt],0,0,0);
        oacc[mt][nt]=__builtin_amdgcn_mfma_f32_16x16x32_bf16(Afl,Boh[nt],oacc[mt][nt],0,0,0);
        oacc[mt][nt]=__builtin_amdgcn_mfma_f32_16x16x32_bf16(Afh,Bol[nt],oacc[mt][nt],0,0,0);
      }
    }
  }
  __syncthreads();
  float* pout=(float*)s_mem;   // alias W1 region: 4 waves x [32][64] fp32 (32KB)
  #pragma unroll
  for (int mt=0;mt<2;mt++)
    #pragma unroll
    for (int nt=0;nt<4;nt++)
      #pragma unroll
      for (int q=0;q<4;q++){
        int row=mt*16+khi*4+q, col=nt*16+lanelo;
        pout[wv*2048 + row*64 + col]=oacc[mt][nt][q];
      }
  __syncthreads();
  const size_t nb=(size_t)n*1600;
  float accn=0.0f;
  for (int j=tid;j<1600;j+=256){
    float v = x[nb+j] + pout[j]+pout[2048+j]+pout[4096+j]+pout[6144+j];
    x[nb+j]=v;
    accn += v*v;
  }
  __syncthreads();   // pout reads done -> safe to alias
  float* s_part=(float*)s_mem;
  float* s_msv=((float*)s_mem)+256;
  s_part[tid]=accn;
  __syncthreads();
  if (tid<64){
    float m=(s_part[tid]+s_part[tid+64]+s_part[tid+128]+s_part[tid+192])*(1.0f/25.0f);
    s_msv[tid]=rsqrtf(m+1e-6f);
  }
  __syncthreads();
  for (int j=tid;j<1600;j+=256){
    int l=j>>6, c=j&63;
    xnout[nb+j]=x[nb+j]*s_msv[c]*nw[d_loc[l]*64+c];
  }
}

// ---------------- final energy head via split-bf16 MFMA ----------------
__global__ __launch_bounds__(256) void energy_mfma_kernel(const float* __restrict__ xn,
    const unsigned short* __restrict__ tgp, const float* __restrict__ fg,
    const unsigned short* __restrict__ enw1p, const float* __restrict__ b1,
    const float* __restrict__ w2, const float* __restrict__ b2,
    float* __restrict__ out, int N){
  int n=blockIdx.x, tid=threadIdx.x, wv=tid>>6, lane=tid&63;
  int lanelo=lane&15, khi=lane>>4;
  __shared__ __align__(16) char s_mem[59584];
  unsigned short* s_w1=(unsigned short*)s_mem;             // hi 8192 | lo 8192 shorts
  unsigned short* s_xn=(unsigned short*)(s_mem+32768);     // hi 2048 | lo 2048
  float* s_b1=(float*)(s_mem+40960);
  float* s_w2=(float*)(s_mem+41472);
  float* s_fg0=(float*)(s_mem+41984);                      // 288 f
  float* s_red=(float*)(s_mem+43136);
  unsigned short* scr=(unsigned short*)(s_mem+43200)+(size_t)wv*2048;  // 4KB/wave (g hi|lo)
  for (int j=tid;j<2048;j+=256) ((int4*)s_w1)[j]=((const int4*)enw1p)[j];
  if (tid<128){ s_b1[tid]=b1[tid]; s_w2[tid]=w2[tid]; }
  for (int j=tid;j<288;j+=256) s_fg0[j]=fg[j];
  { int4 z={0,0,0,0}; for (int j=tid;j<512;j+=256) ((int4*)s_xn)[j]=z; }
  __syncthreads();
  {
    const float* xr=xn+(size_t)n*1600;
    for (int j=tid;j<1600;j+=256){
      int k=j>>6, c=j&63;
      float v=xr[j];
      unsigned short h=f2bf(v);
      s_xn[c*32+k]=h;
      s_xn[2048+c*32+k]=f2bf(v-bf2f(h));
    }
  }
  __syncthreads();
  bf16x8 XBh[4],XBl[4];
  #pragma unroll
  for (int ct=0;ct<4;ct++){
    int o=(ct*16+lanelo)*32 + khi*8;
    XBh[ct]=*(const bf16x8*)(s_xn+o);
    XBl[ct]=*(const bf16x8*)(s_xn+2048+o);
  }
  float b2v=b2[0];
  float e=0.0f;
  for (int t=wv;t<18;t+=4){
    bf16x8 Atgh=*(const bf16x8*)(tgp + t*512 + lane*8);
    bf16x8 Atgl=*(const bf16x8*)(tgp + 9216 + t*512 + lane*8);
    #pragma unroll
    for (int ct=0;ct<4;ct++){
      f32x4 g={0,0,0,0};
      g=__builtin_amdgcn_mfma_f32_16x16x32_bf16(Atgh,XBh[ct],g,0,0,0);
      g=__builtin_amdgcn_mfma_f32_16x16x32_bf16(Atgl,XBh[ct],g,0,0,0);
      g=__builtin_amdgcn_mfma_f32_16x16x32_bf16(Atgh,XBl[ct],g,0,0,0);
      #pragma unroll
      for (int q=0;q<4;q++){
        int row=khi*4+q, col=ct*16+lanelo;
        int pos=row*64 + (((col>>3)^(row&7))<<3) + (col&7);
        float v=g[q]; unsigned short h=f2bf(v);
        scr[pos]=h; scr[1024+pos]=f2bf(v-bf2f(h));
      }
    }
    bf16x8 Agh[2],Agl[2];
    #pragma unroll
    for (int kt=0;kt<2;kt++){
      int o=lanelo*64 + (((kt*4+khi)^(lanelo&7))<<3);
      Agh[kt]=*(const bf16x8*)(scr+o);
      Agl[kt]=*(const bf16x8*)(scr+1024+o);
    }
    #pragma unroll
    for (int nt=0;nt<8;nt++){
      f32x4 h={0,0,0,0};
      #pragma unroll
      for (int kt=0;kt<2;kt++){
        bf16x8 Bh=*(const bf16x8*)(s_w1 + (kt*8+nt)*512 + lane*8);
        bf16x8 Bl=*(const bf16x8*)(s_w1 + 8192 + (kt*8+nt)*512 + lane*8);
        h=__builtin_amdgcn_mfma_f32_16x16x32_bf16(Agh[kt],Bh,h,0,0,0);
        h=__builtin_amdgcn_mfma_f32_16x16x32_bf16(Agl[kt],Bh,h,0,0,0);
        h=__builtin_amdgcn_mfma_f32_16x16x32_bf16(Agh[kt],Bl,h,0,0,0);
      }
      #pragma unroll
      for (int q=0;q<4;q++){
        int row=khi*4+q, col=nt*16+lanelo;
        float v=silu_f(h[q]+s_b1[col]);
        e += v*s_w2[col]*s_fg0[t*16+row];
      }
    }
    if (lanelo==0){
      #pragma unroll
      for (int q=0;q<4;q++) e += s_fg0[t*16+khi*4+q]*b2v;
    }
  }
  #pragma unroll
  for (int d=1;d<64;d<<=1) e += __shfl_xor(e,d);
  if (lane==0) s_red[wv]=e;
  __syncthreads();
  if (tid==0) out[n]=(s_red[0]+s_red[1]+s_red[2]+s_red[3])*(1.0f/2000.0f);
}

extern "C" void kernel_launch(void* const* d_in, const int* in_sizes, int n_in,
                              void* d_out, int out_size, void* d_ws, size_t ws_size,
                              hipStream_t stream){
  (void)n_in; (void)out_size; (void)ws_size;
  const float* ev   = (const float*)d_in[0];
  const float* wig  = (const float*)d_in[1];
  const float* winv = (const float*)d_in[2];
  const float* spe  = (const float*)d_in[3];
  const float* ese  = (const float*)d_in[4];
  const float* degW1= (const float*)d_in[5];
  const float* degb1= (const float*)d_in[6];
  const float* degW2= (const float*)d_in[7];
  const float* degb2= (const float*)d_in[8];
  const float* n1w  = (const float*)d_in[9];
  const float* radW1= (const float*)d_in[10];
  const float* radb1= (const float*)d_in[11];
  const float* radW2= (const float*)d_in[12];
  const float* radb2= (const float*)d_in[13];
  const float* so2W = (const float*)d_in[14];
  const float* aW   = (const float*)d_in[15];
  const float* aV   = (const float*)d_in[16];
  const float* vW   = (const float*)d_in[17];
  const float* pW   = (const float*)d_in[18];
  const float* n2w  = (const float*)d_in[19];
  const float* fW1  = (const float*)d_in[20];
  const float* fb1  = (const float*)d_in[21];
  const float* fW2  = (const float*)d_in[22];
  const float* tg   = (const float*)d_in[23];
  const float* fg   = (const float*)d_in[24];
  const float* fnw  = (const float*)d_in[25];
  const float* enW1 = (const float*)d_in[26];
  const float* enb1 = (const float*)d_in[27];
  const float* enW2 = (const float*)d_in[28];
  const float* enb2 = (const float*)d_in[29];
  const int* nsp = (const int*)d_in[30];
  const int* snd = (const int*)d_in[31];
  const int* rcv = (const int*)d_in[32];
  int N = in_sizes[30];
  int E = in_sizes[31];
  float* out = (float*)d_out;

  float* ws = (float*)d_ws;
  size_t off = 0;
  unsigned short* rad0b = (unsigned short*)(ws + off); off += (size_t)E*192;  // E*384 bf16
  unsigned short* rad1b = (unsigned short*)(ws + off); off += (size_t)E*192;  // E*384 bf16
  float* logits = ws + off; off += (size_t)E*8;
  float* mx     = ws + off; off += (size_t)N*8;
  float* den    = ws + off; off += (size_t)N*8;
  float* x      = ws + off; off += (size_t)N*1600;
  float* xn     = ws + off; off += (size_t)N*1600;
  unsigned short* wsvb  = (unsigned short*)(ws + off); off += (size_t)6*16384/2;
  unsigned short* projb = (unsigned short*)(ws + off); off += (size_t)6*8192/2;
  int* cnt      = (int*)(ws + off); off += (size_t)N;
  int* rowptr   = (int*)(ws + off); off += (size_t)(N+1);
  int* fill     = (int*)(ws + off); off += (size_t)N;
  int* eixbuf   = (int*)(ws + off); off += (size_t)E;
  off = (off + 3) & ~((size_t)3);                       // 16B-align
  unsigned short* msgb  = (unsigned short*)(ws + off); off += (size_t)E*1216;  // [E][19][128] bf16
  unsigned short* tgp   = (unsigned short*)(ws + off); off += 9216;    // hi+lo 18432 shorts
  unsigned short* fgp   = (unsigned short*)(ws + off); off += 18432;   // hi+lo 36864 shorts
  unsigned short* wwp   = (unsigned short*)(ws + off); off += 32768;   // 2 layers x (w1 hi/lo + w2 hi/lo)
  unsigned short* enw1p = (unsigned short*)(ws + off); off += 8192;    // hi+lo 16384 shorts
  unsigned short* degw1p = (unsigned short*)(ws + off); off += 94208;   // 23*8*512 *2
  unsigned short* degw2p = (unsigned short*)(ws + off); off += 155648;  // 4*76*512 *2
  unsigned short* radw1p = (unsigned short*)(ws + off); off += 94208*2; // per layer
  unsigned short* radw2p = (unsigned short*)(ws + off); off += 49152*2; // per layer

  // CSR build (ordered chain) + ONE pack dispatch for all weight reformats
  zero_cnt_kernel<<<(N+255)/256, 256, 0, stream>>>(cnt, N);
  csr_count_kernel<<<(E+255)/256, 256, 0, stream>>>(rcv, cnt, E);
  csr_scan_kernel<<<1, 256, 0, stream>>>(cnt, rowptr, fill, N);
  csr_fill_kernel<<<(E+255)/256, 256, 0, stream>>>(rcv, fill, eixbuf, E);
  pack_all_kernel<<<210, 256, 0, stream>>>(so2W, vW, wsvb, pW, projb,
      tg, tgp, fg, fgp, fW1, fW2, wwp, enW1, enw1p,
      degW1, degw1p, degW2, degw2p, radW1, radw1p, radW2, radw2p);

  // ONE mlpf dispatch, 2x grid: deg+rad0 blocks + rad1-only blocks run concurrently
  int nb0 = (E+15)/16;
  mlpf_kernel<<<2*nb0, 256, 0, stream>>>(ev, ese, nsp,
      degw1p, degw1p+94208, degb1, degw2p, degw2p+155648, degb2,
      radw1p, radw1p+94208, radb1,
      radw2p, radw2p+49152, radb2,
      radw1p+188416, radw1p+188416+94208, radb1+128,
      radw2p+98304, radw2p+98304+49152, radb2+384,
      snd, rcv, eixbuf, msgb, rad0b, rad1b, nb0, E);
  node_sum_kernel<<<N, 256, 0, stream>>>(msgb, winv, rowptr, eixbuf, nsp, spe,
                                         n1w, x, xn, mx, den, 1, N);

  for (int i=0;i<2;i++){
    const unsigned short* radp = (i==0)? rad0b : rad1b;
    msg_kernel<<<(E+3)/4, 256, 0, stream>>>(xn, wig, radp,
                                            so2W + (size_t)i*24576,
                                            aW + (size_t)i*64*256, aV + (size_t)i*256,
                                            snd, rcv, eixbuf, msgb, logits, mx, E);
    den_kernel<<<(E*8+255)/256, 256, 0, stream>>>(logits, mx, rcv, den, E);
    attn_gemm_kernel<<<(E+15)/16, 256, 0, stream>>>(msgb,
                                                    wsvb + (size_t)i*3*16384, projb + (size_t)i*3*8192,
                                                    logits, mx, den, eixbuf, rcv, E);
    node_sum_kernel<<<N, 256, 0, stream>>>(msgb, winv, rowptr, eixbuf, nsp, spe,
                                           n2w + (size_t)i*320, x, xn, mx, den, 0, N);
    const float* nxt = (i==0) ? (n1w + 320) : fnw;
    grid_ffn_mfma_kernel<<<N, 256, 0, stream>>>(xn, tgp, fgp,
                                                wwp + (size_t)i*32768, wwp + (size_t)i*32768 + 16384,
                                                fb1 + (size_t)i*128, nxt, x, xn, N);
  }
  energy_mfma_kernel<<<N, 256, 0, stream>>>(xn, tgp, fg, enw1p, enb1, enW2, enb2, out, N);
}